// Round 15
// baseline (681.731 us; speedup 1.0000x reference)
//
#include <hip/hip_runtime.h>
#include <math.h>

// Problem constants (from reference)
constexpr int NN = 100000;          // nodes
constexpr int EE = 6400000;         // edges
constexpr int FF = 6;               // features
constexpr int RG = 500;             // reg head hidden
constexpr double MM = 600000.0;     // N*F elements for global norm

constexpr int NODE_BLOCK = 256;
constexpr int NODE_GRID  = (NN + NODE_BLOCK - 1) / NODE_BLOCK;   // 391

constexpr int CHUNK = 8192;
constexpr int NBLK  = (EE + CHUNK - 1) / CHUNK;  // 782
constexpr int SUB   = 4096;                      // pass-A LDS sort sub-batch
constexpr int NSUBB = CHUNK / SUB;               // 2
constexpr int SUBA  = 1024;                      // attach sub-batch
constexpr int NSUBA = CHUNK / SUBA;              // 8
constexpr int SBSH  = 9;                         // src window = 512 nodes
constexpr int NSB   = (NN + (1 << SBSH) - 1) >> SBSH;   // 196
constexpr int DBSH  = 9;                         // dst bucket = 512 nodes
constexpr int DBN   = 1 << DBSH;                 // 512
constexpr int NBDST = (NN + DBN - 1) >> DBSH;    // 196
constexpr int PSEG  = 8;                         // segments per bucket (dl-sort)
constexpr int SUBP  = 1024;                      // permute sub-batch
constexpr int QSD   = 10;                        // fallback gather slices
constexpr int ACCW  = 7 * DBN;                   // fallback partial width
constexpr int GNPB  = 128;                       // gather_node blocks per bucket (512/4)

typedef unsigned uv2 __attribute__((ext_vector_type(2)));
typedef unsigned uv4 __attribute__((ext_vector_type(4)));
typedef float    fv2 __attribute__((ext_vector_type(2)));

__device__ __forceinline__ float leakyf(float v, float s) { return v >= 0.f ? v : s * v; }

__device__ __forceinline__ unsigned f2bf(float x) {   // RNE f32 -> bf16 bits
    unsigned u = __float_as_uint(x);
    return (u + 0x7FFFu + ((u >> 16) & 1u)) >> 16;
}

__device__ __forceinline__ void norm_params(const double* __restrict__ S, float& mu, float& istd) {
    double s1 = S[0], s2 = S[1];
    double mean = s1 / MM;
    double var  = (s2 - s1 * mean) / (MM - 1.0);
    mu   = (float)mean;
    istd = (float)(1.0 / sqrt(var));
}

// K0: collapse regression head; zero norm scalars.
__global__ void head_prep(const float* __restrict__ Wresh, const float* __restrict__ bresh,
                          const float* __restrict__ W1, const float* __restrict__ b1,
                          const float* __restrict__ W2, const float* __restrict__ b2,
                          float* __restrict__ head, double* __restrict__ S) {
    int t = threadIdx.x;
    if (t < 8) S[t] = 0.0;
    if (t < FF) {
        float a1 = 0.f, a2 = 0.f;
        for (int g = 0; g < RG; ++g) {
            float w = Wresh[t * RG + g];
            a1 = fmaf(w, W1[g], a1);
            a2 = fmaf(w, W2[g], a2);
        }
        head[t]     = a1;
        head[8 + t] = a2;
    } else if (t == FF) {
        float a1 = 0.f, a2 = 0.f;
        for (int g = 0; g < RG; ++g) {
            a1 = fmaf(bresh[g], W1[g], a1);
            a2 = fmaf(bresh[g], W2[g], a2);
        }
        head[6]  = a1 + b1[0];
        head[14] = a2 + b2[0];
    }
}

__global__ __launch_bounds__(256)
void finish_norm(const double* __restrict__ part, int cnt, double* __restrict__ S) {
    __shared__ double sh[8];
    int wid = threadIdx.x >> 6, lane = threadIdx.x & 63;
    double s1 = 0.0, s2 = 0.0;
    for (int i = threadIdx.x; i < cnt; i += 256) {
        s1 += part[2 * i];
        s2 += part[2 * i + 1];
    }
    #pragma unroll
    for (int o = 32; o > 0; o >>= 1) {
        s1 += __shfl_down(s1, o, 64);
        s2 += __shfl_down(s2, o, 64);
    }
    if (lane == 0) { sh[wid * 2] = s1; sh[wid * 2 + 1] = s2; }
    __syncthreads();
    if (threadIdx.x == 0) {
        S[0] = sh[0] + sh[2] + sh[4] + sh[6];
        S[1] = sh[1] + sh[3] + sh[5] + sh[7];
    }
}

// ---------- pass A: bin by src-window ----------

__global__ __launch_bounds__(256)
void hist_src(const int* __restrict__ ei, unsigned* __restrict__ cntA) {
    __shared__ unsigned hist[NSB];
    for (int b = threadIdx.x; b < NSB; b += 256) hist[b] = 0u;
    __syncthreads();
    int e0 = blockIdx.x * CHUNK;
    for (int i = threadIdx.x; i < CHUNK; i += 256) {
        int e = e0 + i;
        if (e < EE) {
            int s = __builtin_nontemporal_load(ei + e) % NN;
            atomicAdd(&hist[s >> SBSH], 1u);
        }
    }
    __syncthreads();
    for (int b = threadIdx.x; b < NSB; b += 256)
        cntA[(size_t)blockIdx.x * NSB + b] = hist[b];
}

template <int NBINS>
__global__ __launch_bounds__(1024)
void scan_bins(unsigned* __restrict__ cnt, unsigned* __restrict__ tot) {
    __shared__ unsigned ls[1024];
    int b = blockIdx.x, t = threadIdx.x;
    unsigned v = (t < NBLK) ? cnt[(size_t)t * NBINS + b] : 0u;
    ls[t] = v;
    __syncthreads();
    for (int o = 1; o < 1024; o <<= 1) {
        unsigned add = (t >= o) ? ls[t - o] : 0u;
        __syncthreads();
        ls[t] += add;
        __syncthreads();
    }
    if (t < NBLK) cnt[(size_t)t * NBINS + b] = ls[t] - v;
    if (t == 1023) tot[b] = ls[1023];
}

__global__ __launch_bounds__(1024)
void scan_totals(const unsigned* __restrict__ tot, int* __restrict__ start, int n) {
    __shared__ unsigned ls[1024];
    int t = threadIdx.x;
    unsigned v = (t < n) ? tot[t] : 0u;
    ls[t] = v;
    __syncthreads();
    for (int o = 1; o < 1024; o <<= 1) {
        unsigned add = (t >= o) ? ls[t - o] : 0u;
        __syncthreads();
        ls[t] += add;
        __syncthreads();
    }
    if (t < n) start[t] = (int)(ls[t] - v);
    if (t == 1023) start[n] = (int)ls[1023];
}

// pass A scatter: SoA kv = {src | dl<<17, ea 2xbf16} (8B), bk = dst bucket (1B)
__global__ __launch_bounds__(512)
void scatter_src(const int* __restrict__ ei, const float* __restrict__ eattr,
                 const unsigned* __restrict__ cntA, const int* __restrict__ segStart,
                 uv2* __restrict__ kv, unsigned char* __restrict__ bk) {
    __shared__ unsigned cur[NSB];
    __shared__ unsigned hist[NSB];
    __shared__ unsigned scn[256];
    __shared__ uv2 stage[SUB];
    __shared__ unsigned char stageB[SUB];
    int blk = blockIdx.x;
    int tid = threadIdx.x;
    for (int b = tid; b < NSB; b += 512)
        cur[b] = (unsigned)segStart[b] + cntA[(size_t)blk * NSB + b];
    int e0 = blk * CHUNK;
    for (int s = 0; s < NSUBB; ++s) {
        for (int b = tid; b < NSB; b += 512) hist[b] = 0u;
        __syncthreads();
        int sb0 = e0 + s * SUB;
        unsigned rk[8]; uv2 rc[8]; int bn[8]; unsigned char bb[8]; bool val[8];
        #pragma unroll
        for (int j = 0; j < 8; ++j) {
            int e = sb0 + j * 512 + tid;
            val[j] = e < EE;
            int ss = 0, dd = 0;
            fv2 ea; ea.x = 0.f; ea.y = 0.f;
            if (val[j]) {
                ss = __builtin_nontemporal_load(ei + e) % NN;
                dd = __builtin_nontemporal_load(ei + EE + e) % NN;
                ea = __builtin_nontemporal_load(reinterpret_cast<const fv2*>(eattr) + e);
            }
            bn[j] = ss >> SBSH;
            rc[j].x = (unsigned)ss | ((unsigned)(dd & (DBN - 1)) << 17);
            rc[j].y = f2bf(ea.x) | (f2bf(ea.y) << 16);
            bb[j] = (unsigned char)(dd >> DBSH);
            if (val[j]) rk[j] = atomicAdd(&hist[bn[j]], 1u);
        }
        __syncthreads();
        if (tid < 256) scn[tid] = (tid < NSB) ? hist[tid] : 0u;
        __syncthreads();
        for (int o = 1; o < 256; o <<= 1) {
            unsigned add = 0u;
            if (tid < 256 && tid >= o) add = scn[tid - o];
            __syncthreads();
            if (tid < 256) scn[tid] += add;
            __syncthreads();
        }
        #pragma unroll
        for (int j = 0; j < 8; ++j) {
            if (val[j]) {
                unsigned ex = bn[j] ? scn[bn[j] - 1] : 0u;
                stage[ex + rk[j]]  = rc[j];
                stageB[ex + rk[j]] = bb[j];
            }
        }
        __syncthreads();
        int subCnt = (int)scn[NSB - 1];
        for (int i = tid; i < subCnt; i += 512) {
            uv2 r = stage[i];
            unsigned b = (r.x & 0x1FFFFu) >> SBSH;
            unsigned ex = b ? scn[b - 1] : 0u;
            unsigned pos = cur[b] + (unsigned)i - ex;
            kv[pos] = r;
            bk[pos] = stageB[i];
        }
        __syncthreads();
        for (int b = tid; b < NSB; b += 512) cur[b] += hist[b];
        __syncthreads();
    }
}

// ---------- pass B histogram (dst buckets; graph-only) ----------

__global__ __launch_bounds__(256)
void hist_dst(const unsigned char* __restrict__ bk, unsigned* __restrict__ cntB) {
    __shared__ unsigned hist[NBDST];
    for (int b = threadIdx.x; b < NBDST; b += 256) hist[b] = 0u;
    __syncthreads();
    int e0 = blockIdx.x * CHUNK;
    for (int i = threadIdx.x; i < CHUNK; i += 256) {
        int e = e0 + i;
        if (e < EE) atomicAdd(&hist[bk[e]], 1u);
    }
    __syncthreads();
    for (int b = threadIdx.x; b < NBDST; b += 256)
        cntB[(size_t)blockIdx.x * NBDST + b] = hist[b];
}

// ---------- per-layer attach + bucket scatter (R13, proven) ----------
__global__ __launch_bounds__(512)
void scatter_dst_att(const uv2* __restrict__ kv, const unsigned char* __restrict__ bk,
                     const unsigned* __restrict__ cntB, const int* __restrict__ bstart,
                     const int* __restrict__ segStart, const uv4* __restrict__ xlb,
                     uv4* __restrict__ recsA, unsigned short* __restrict__ recsD) {
    __shared__ unsigned cur[NBDST];
    __shared__ unsigned hist[NBDST];
    __shared__ unsigned scn[256];
    __shared__ uv4 win[2][DBN];
    __shared__ uv4 stA[SUBA];
    __shared__ unsigned short stD[SUBA];
    __shared__ unsigned char sbin[SUBA];
    __shared__ int w0s;
    int blk = blockIdx.x;
    int tid = threadIdx.x;
    int e0 = blk * CHUNK;
    if (tid == 0) w0s = 0;
    __syncthreads();
    if (tid < NSB && segStart[tid] <= e0 && e0 < segStart[tid + 1]) w0s = tid;
    __syncthreads();
    int w0 = w0s;
    int w1 = min(w0 + 1, NSB - 1);
    for (int i = tid; i < DBN; i += 512) {
        int g0 = (w0 << SBSH) + i;
        int g1 = (w1 << SBSH) + i;
        uv4 z; z.x = 0u; z.y = 0u; z.z = 0u; z.w = 0u;
        win[0][i] = (g0 < NN) ? xlb[g0] : z;
        win[1][i] = (g1 < NN) ? xlb[g1] : z;
    }
    for (int b = tid; b < NBDST; b += 512)
        cur[b] = (unsigned)bstart[b] + cntB[(size_t)blk * NBDST + b];
    __syncthreads();

    for (int s = 0; s < NSUBA; ++s) {
        for (int b = tid; b < NBDST; b += 512) hist[b] = 0u;
        __syncthreads();
        int sb0 = e0 + s * SUBA;
        unsigned rk[2]; uv4 rc[2]; unsigned short dl2[2]; int bn[2]; bool val[2];
        #pragma unroll
        for (int j = 0; j < 2; ++j) {
            int e = sb0 + j * 512 + tid;
            val[j] = e < EE;
            uv2 r; r.x = 0u; r.y = 0u;
            int b = 0;
            if (val[j]) {
                r = __builtin_nontemporal_load(kv + e);
                b = (int)bk[e];
            }
            int src = (int)(r.x & 0x1FFFFu);
            int sel = min(max((src >> SBSH) - w0, 0), 1);
            uv4 q = win[sel][src & (DBN - 1)];
            rc[j].x = r.y;
            rc[j].y = q.x;
            rc[j].z = q.y;
            rc[j].w = q.z;
            dl2[j] = (unsigned short)((r.x >> 17) & (DBN - 1));
            bn[j] = b;
            if (val[j]) rk[j] = atomicAdd(&hist[bn[j]], 1u);
        }
        __syncthreads();
        if (tid < 256) scn[tid] = (tid < NBDST) ? hist[tid] : 0u;
        __syncthreads();
        for (int o = 1; o < 256; o <<= 1) {
            unsigned add = 0u;
            if (tid < 256 && tid >= o) add = scn[tid - o];
            __syncthreads();
            if (tid < 256) scn[tid] += add;
            __syncthreads();
        }
        #pragma unroll
        for (int j = 0; j < 2; ++j) {
            if (val[j]) {
                unsigned ex = bn[j] ? scn[bn[j] - 1] : 0u;
                unsigned p = ex + rk[j];
                stA[p] = rc[j];
                stD[p] = dl2[j];
                sbin[p] = (unsigned char)bn[j];
            }
        }
        __syncthreads();
        int subCnt = (int)scn[NBDST - 1];
        for (int i = tid; i < subCnt; i += 512) {
            unsigned b = sbin[i];
            unsigned ex = b ? scn[b - 1] : 0u;
            unsigned pos = cur[b] + (unsigned)i - ex;
            recsA[pos] = stA[i];
            recsD[pos] = stD[i];
        }
        __syncthreads();
        for (int b = tid; b < NBDST; b += 512) cur[b] += hist[b];
        __syncthreads();
    }
}

// ---------- per-layer dl-sort ----------
__global__ __launch_bounds__(256)
void hist_dl(const unsigned short* __restrict__ recsD, const int* __restrict__ bstart,
             unsigned* __restrict__ cntC) {
    __shared__ unsigned hist[DBN];
    int b = blockIdx.x / PSEG, s = blockIdx.x % PSEG;
    int b0 = bstart[b], b1 = bstart[b + 1], len = b1 - b0;
    int k0 = b0 + (int)(((long long)len * s) / PSEG);
    int k1 = b0 + (int)(((long long)len * (s + 1)) / PSEG);
    for (int i = threadIdx.x; i < DBN; i += 256) hist[i] = 0u;
    __syncthreads();
    for (int k = k0 + threadIdx.x; k < k1; k += 256)
        atomicAdd(&hist[recsD[k]], 1u);
    __syncthreads();
    unsigned* row = cntC + (size_t)blockIdx.x * DBN;
    for (int i = threadIdx.x; i < DBN; i += 256) row[i] = hist[i];
}

__global__ __launch_bounds__(512)
void scan_dl(unsigned* __restrict__ cntC, const int* __restrict__ bstart,
             int* __restrict__ nstart) {
    __shared__ unsigned dlt[DBN];
    __shared__ unsigned scn[DBN];
    int b = blockIdx.x, dl = threadIdx.x;
    unsigned run = 0;
    for (int s = 0; s < PSEG; ++s) {
        size_t idx = ((size_t)(b * PSEG + s)) * DBN + dl;
        unsigned v = cntC[idx];
        cntC[idx] = run;
        run += v;
    }
    dlt[dl] = run;
    scn[dl] = run;
    __syncthreads();
    for (int o = 1; o < DBN; o <<= 1) {
        unsigned add = (dl >= o) ? scn[dl - o] : 0u;
        __syncthreads();
        scn[dl] += add;
        __syncthreads();
    }
    unsigned base = (unsigned)bstart[b] + (scn[dl] - dlt[dl]);
    for (int s = 0; s < PSEG; ++s) {
        size_t idx = ((size_t)(b * PSEG + s)) * DBN + dl;
        cntC[idx] += base;
    }
    nstart[(b << DBSH) + dl] = (int)base;
    if (b == NBDST - 1 && dl == DBN - 1) nstart[NBDST << DBSH] = (int)(base + dlt[dl]);
}

// grouped permute: buckets [g0 ..), writes group-relative into recsAdH
__global__ __launch_bounds__(512)
void permute_rec(const uv4* __restrict__ recsAs, const unsigned short* __restrict__ recsDs,
                 const unsigned* __restrict__ cntC, const int* __restrict__ bstart,
                 uv4* __restrict__ recsAdH, int g0) {
    __shared__ unsigned cur[DBN];
    __shared__ unsigned hist[DBN];
    __shared__ unsigned scn[DBN];
    __shared__ uv4 stA[SUBP];
    __shared__ unsigned short sbin[SUBP];
    int b = g0 + blockIdx.x / PSEG, s = blockIdx.x % PSEG;
    unsigned gbase = (unsigned)bstart[g0];
    int b0 = bstart[b], b1 = bstart[b + 1], len = b1 - b0;
    int k0 = b0 + (int)(((long long)len * s) / PSEG);
    int k1 = b0 + (int)(((long long)len * (s + 1)) / PSEG);
    int tid = threadIdx.x;
    const unsigned* row = cntC + (size_t)(b * PSEG + s) * DBN;
    for (int i = tid; i < DBN; i += 512) cur[i] = row[i] - gbase;
    for (int sb0 = k0; sb0 < k1; sb0 += SUBP) {
        for (int i = tid; i < DBN; i += 512) hist[i] = 0u;
        __syncthreads();
        unsigned rk[2]; uv4 rc[2]; int bn[2]; bool val[2];
        #pragma unroll
        for (int j = 0; j < 2; ++j) {
            int k = sb0 + j * 512 + tid;
            val[j] = k < k1;
            uv4 r; r.x = 0u; r.y = 0u; r.z = 0u; r.w = 0u;
            int d = 0;
            if (val[j]) {
                r = __builtin_nontemporal_load(recsAs + k);
                d = (int)recsDs[k];
            }
            rc[j] = r;
            bn[j] = d;
            if (val[j]) rk[j] = atomicAdd(&hist[d], 1u);
        }
        __syncthreads();
        scn[tid] = hist[tid];
        __syncthreads();
        for (int o = 1; o < DBN; o <<= 1) {
            unsigned add = (tid >= o) ? scn[tid - o] : 0u;
            __syncthreads();
            scn[tid] += add;
            __syncthreads();
        }
        #pragma unroll
        for (int j = 0; j < 2; ++j) {
            if (val[j]) {
                unsigned ex = bn[j] ? scn[bn[j] - 1] : 0u;
                unsigned p = ex + rk[j];
                stA[p] = rc[j];
                sbin[p] = (unsigned short)bn[j];
            }
        }
        __syncthreads();
        int subCnt = (int)scn[DBN - 1];
        for (int i = tid; i < subCnt; i += 512) {
            unsigned d = sbin[i];
            unsigned ex = d ? scn[d - 1] : 0u;
            recsAdH[cur[d] + (unsigned)i - ex] = stA[i];
        }
        __syncthreads();
        for (int i = tid; i < DBN; i += 512) cur[i] += hist[i];
        __syncthreads();
    }
}

// ---------- node transform: xlb + xrb, both bf16 packed (16B/node) ----------
template <int LAYER>
__global__ __launch_bounds__(NODE_BLOCK)
void node_transform(const float* __restrict__ xin, const double* __restrict__ Snorm,
                    const float* __restrict__ Wl, const float* __restrict__ bl,
                    const float* __restrict__ Wr, const float* __restrict__ br,
                    uv4* __restrict__ xlb, uv4* __restrict__ xrb,
                    float* __restrict__ x2out) {
    int n = blockIdx.x * blockDim.x + threadIdx.x;
    if (n >= NN) return;
    float v[FF];
    if (LAYER == 0) {
        #pragma unroll
        for (int f = 0; f < FF; ++f) v[f] = xin[n * FF + f];
    } else {
        float mu, istd;
        norm_params(Snorm, mu, istd);
        #pragma unroll
        for (int f = 0; f < FF; ++f) {
            v[f] = (xin[n * FF + f] - mu) * istd;
            x2out[n * FF + f] = v[f];
        }
    }
    float ol[FF], orr[FF];
    #pragma unroll
    for (int j = 0; j < FF; ++j) { ol[j] = bl[j]; orr[j] = br[j]; }
    #pragma unroll
    for (int k = 0; k < FF; ++k) {
        float vk = v[k];
        #pragma unroll
        for (int j = 0; j < FF; ++j) {
            ol[j]  = fmaf(vk, Wl[k * FF + j], ol[j]);
            orr[j] = fmaf(vk, Wr[k * FF + j], orr[j]);
        }
    }
    uv4 q;
    q.x = f2bf(ol[0]) | (f2bf(ol[1]) << 16);
    q.y = f2bf(ol[2]) | (f2bf(ol[3]) << 16);
    q.z = f2bf(ol[4]) | (f2bf(ol[5]) << 16);
    q.w = 0u;
    xlb[n] = q;
    uv4 r;
    r.x = f2bf(orr[0]) | (f2bf(orr[1]) << 16);
    r.y = f2bf(orr[2]) | (f2bf(orr[3]) << 16);
    r.z = f2bf(orr[4]) | (f2bf(orr[5]) << 16);
    r.w = 0u;
    xrb[n] = r;
}

// ---------- FAST gather: one wave per node, register reduce, ZERO atomics ----------
template <int LAYER>
__global__ __launch_bounds__(256)
void gather_node(const int* __restrict__ nstart, const uv4* __restrict__ recsAdH,
                 const uv4* __restrict__ xrb,
                 const float* __restrict__ Wef, const float* __restrict__ attf,
                 const float* __restrict__ biasg,
                 const float* __restrict__ x0, const float* __restrict__ x1n0,
                 const float* __restrict__ x2,
                 float* __restrict__ h, double* __restrict__ part,
                 const int* __restrict__ bstart, int g0) {
    __shared__ double shd[8];
    int wid  = threadIdx.x >> 6;
    int lane = threadIdx.x & 63;
    int n = (g0 << DBSH) + blockIdx.x * 4 + wid;
    int gbase = bstart[g0];
    double s1 = 0.0, s2 = 0.0;
    if (n < NN) {
        float we0[FF], we1[FF], at[FF];
        #pragma unroll
        for (int f = 0; f < FF; ++f) { we0[f] = Wef[f]; we1[f] = Wef[FF + f]; at[f] = attf[f]; }
        uv4 r = xrb[n];
        float bv[FF];
        bv[0] = __uint_as_float(r.x << 16);  bv[1] = __uint_as_float(r.x & 0xFFFF0000u);
        bv[2] = __uint_as_float(r.y << 16);  bv[3] = __uint_as_float(r.y & 0xFFFF0000u);
        bv[4] = __uint_as_float(r.z << 16);  bv[5] = __uint_as_float(r.z & 0xFFFF0000u);

        int k0 = nstart[n] - gbase, k1 = nstart[n + 1] - gbase;
        float dsum = 0.f, ns[FF] = {0.f, 0.f, 0.f, 0.f, 0.f, 0.f};
        for (int k = k0 + lane; k < k1; k += 64) {
            uv4 a = __builtin_nontemporal_load(recsAdH + k);
            float eax = __uint_as_float(a.x << 16);
            float eay = __uint_as_float(a.x & 0xFFFF0000u);
            float av[FF];
            av[0] = __uint_as_float(a.y << 16);  av[1] = __uint_as_float(a.y & 0xFFFF0000u);
            av[2] = __uint_as_float(a.z << 16);  av[3] = __uint_as_float(a.z & 0xFFFF0000u);
            av[4] = __uint_as_float(a.w << 16);  av[5] = __uint_as_float(a.w & 0xFFFF0000u);
            float logit = 0.f;
            #pragma unroll
            for (int f = 0; f < FF; ++f) {
                float m = av[f] + bv[f] + fmaf(eay, we1[f], eax * we0[f]);
                m = m >= 0.f ? m : 0.2f * m;
                logit = fmaf(at[f], m, logit);
            }
            float w = __expf(logit);
            dsum += w;
            #pragma unroll
            for (int f = 0; f < FF; ++f) ns[f] = fmaf(w, av[f], ns[f]);
        }
        #pragma unroll
        for (int o = 1; o < 64; o <<= 1) {
            dsum += __shfl_xor(dsum, o, 64);
            #pragma unroll
            for (int f = 0; f < FF; ++f) ns[f] += __shfl_xor(ns[f], o, 64);
        }
        float inv = dsum != 0.f ? 1.f / dsum : 0.f;
        float myn = ns[0];
        myn = (lane == 1) ? ns[1] : myn;
        myn = (lane == 2) ? ns[2] : myn;
        myn = (lane == 3) ? ns[3] : myn;
        myn = (lane == 4) ? ns[4] : myn;
        myn = (lane == 5) ? ns[5] : myn;
        if (lane < FF) {
            float t = leakyf(myn * inv + biasg[lane], 0.01f);
            t += x0[n * FF + lane];
            if (LAYER == 1) t += x1n0[n * FF + lane] + x2[n * FF + lane];
            h[n * FF + lane] = t;
            s1 = t;
            s2 = (double)t * (double)t;
        }
        #pragma unroll
        for (int o = 1; o < 8; o <<= 1) {
            s1 += __shfl_xor(s1, o, 64);
            s2 += __shfl_xor(s2, o, 64);
        }
    }
    if (lane == 0) { shd[wid * 2] = s1; shd[wid * 2 + 1] = s2; }
    __syncthreads();
    if (threadIdx.x == 0) {
        int pb = g0 * GNPB + blockIdx.x;
        part[pb * 2 + 0] = shd[0] + shd[2] + shd[4] + shd[6];
        part[pb * 2 + 1] = shd[1] + shd[3] + shd[5] + shd[7];
    }
}

// ---------- FALLBACK kernels (R12, proven) ----------
__global__ __launch_bounds__(512)
void scatter_dst(const uv2* __restrict__ kv, const unsigned char* __restrict__ bk,
                 const unsigned* __restrict__ cntB, const int* __restrict__ bstart,
                 uv2* __restrict__ recs) {
    __shared__ unsigned cur[NBDST];
    __shared__ unsigned hist[NBDST];
    __shared__ unsigned scn[256];
    __shared__ uv2 stage[SUB];
    __shared__ unsigned char sbin[SUB];
    int blk = blockIdx.x;
    int tid = threadIdx.x;
    for (int b = tid; b < NBDST; b += 512)
        cur[b] = (unsigned)bstart[b] + cntB[(size_t)blk * NBDST + b];
    int e0 = blk * CHUNK;
    for (int s = 0; s < NSUBB; ++s) {
        for (int b = tid; b < NBDST; b += 512) hist[b] = 0u;
        __syncthreads();
        int sb0 = e0 + s * SUB;
        unsigned rk[8]; uv2 rc[8]; int bn[8]; bool val[8];
        #pragma unroll
        for (int j = 0; j < 8; ++j) {
            int e = sb0 + j * 512 + tid;
            val[j] = e < EE;
            uv2 r; r.x = 0u; r.y = 0u;
            int b = 0;
            if (val[j]) {
                r = __builtin_nontemporal_load(kv + e);
                b = (int)bk[e];
            }
            rc[j] = r;
            bn[j] = b;
            if (val[j]) rk[j] = atomicAdd(&hist[bn[j]], 1u);
        }
        __syncthreads();
        if (tid < 256) scn[tid] = (tid < NBDST) ? hist[tid] : 0u;
        __syncthreads();
        for (int o = 1; o < 256; o <<= 1) {
            unsigned add = 0u;
            if (tid < 256 && tid >= o) add = scn[tid - o];
            __syncthreads();
            if (tid < 256) scn[tid] += add;
            __syncthreads();
        }
        #pragma unroll
        for (int j = 0; j < 8; ++j) {
            if (val[j]) {
                unsigned ex = bn[j] ? scn[bn[j] - 1] : 0u;
                stage[ex + rk[j]] = rc[j];
                sbin[ex + rk[j]] = (unsigned char)bn[j];
            }
        }
        __syncthreads();
        int subCnt = (int)scn[NBDST - 1];
        for (int i = tid; i < subCnt; i += 512) {
            uv2 r = stage[i];
            unsigned b = sbin[i];
            unsigned ex = b ? scn[b - 1] : 0u;
            recs[cur[b] + (unsigned)i - ex] = r;
        }
        __syncthreads();
        for (int b = tid; b < NBDST; b += 512) cur[b] += hist[b];
        __syncthreads();
    }
}

__device__ __forceinline__ void edge_math(unsigned eaw, unsigned a01, unsigned a23, unsigned a45,
                                          int dl, bool valid,
                                          float (&acc)[7][DBN], const uv4* __restrict__ xrl,
                                          const float we0[FF], const float we1[FF],
                                          const float at[FF]) {
    uv4 r = xrl[dl];
    float eax = __uint_as_float(eaw << 16);
    float eay = __uint_as_float(eaw & 0xFFFF0000u);
    float av[FF], bv[FF];
    av[0] = __uint_as_float(a01 << 16);  av[1] = __uint_as_float(a01 & 0xFFFF0000u);
    av[2] = __uint_as_float(a23 << 16);  av[3] = __uint_as_float(a23 & 0xFFFF0000u);
    av[4] = __uint_as_float(a45 << 16);  av[5] = __uint_as_float(a45 & 0xFFFF0000u);
    bv[0] = __uint_as_float(r.x << 16);  bv[1] = __uint_as_float(r.x & 0xFFFF0000u);
    bv[2] = __uint_as_float(r.y << 16);  bv[3] = __uint_as_float(r.y & 0xFFFF0000u);
    bv[4] = __uint_as_float(r.z << 16);  bv[5] = __uint_as_float(r.z & 0xFFFF0000u);
    float logit = 0.f;
    #pragma unroll
    for (int f = 0; f < FF; ++f) {
        float m = av[f] + bv[f] + fmaf(eay, we1[f], eax * we0[f]);
        m = m >= 0.f ? m : 0.2f * m;
        logit = fmaf(at[f], m, logit);
    }
    float w = __expf(logit);
    w = valid ? w : 0.f;
    atomicAdd(&acc[6][dl], w);
    #pragma unroll
    for (int f = 0; f < FF; ++f) atomicAdd(&acc[f][dl], w * av[f]);
}

template <int QSL>
__global__ __launch_bounds__(256)
void gat_gather_div(const int* __restrict__ bucketStart, const uv2* __restrict__ recs,
                    const uv4* __restrict__ xlb, const uv4* __restrict__ xrb,
                    const float* __restrict__ Wef, const float* __restrict__ attf,
                    float* __restrict__ partG) {
    __shared__ float acc[7][DBN];
    __shared__ uv4 xrl[DBN];
    int b  = blockIdx.x / QSL;
    int qq = blockIdx.x % QSL;
    int nb0 = b << DBSH;
    int cnt = min(DBN, NN - nb0);

    for (int i = threadIdx.x; i < 7 * DBN; i += 256) acc[0][i] = 0.f;
    for (int i = threadIdx.x; i < cnt; i += 256) xrl[i] = xrb[nb0 + i];
    float we0[FF], we1[FF], at[FF];
    #pragma unroll
    for (int f = 0; f < FF; ++f) { we0[f] = Wef[f]; we1[f] = Wef[FF + f]; at[f] = attf[f]; }
    __syncthreads();

    int bk0 = bucketStart[b], bk1 = bucketStart[b + 1];
    int len = bk1 - bk0;
    int k0 = bk0 + (int)(((long long)len * qq) / QSL);
    int k1 = bk0 + (int)(((long long)len * (qq + 1)) / QSL);
    int last = k1 - 1;
    for (int base = k0 + threadIdx.x * 4; base < k1; base += 1024) {
        uv2 rA = __builtin_nontemporal_load(recs + base);
        uv2 rB = __builtin_nontemporal_load(recs + min(base + 1, last));
        uv2 rC = __builtin_nontemporal_load(recs + min(base + 2, last));
        uv2 rD = __builtin_nontemporal_load(recs + min(base + 3, last));
        uv4 qA = xlb[rA.x & 0x1FFFF];
        uv4 qB = xlb[rB.x & 0x1FFFF];
        uv4 qC = xlb[rC.x & 0x1FFFF];
        uv4 qD = xlb[rD.x & 0x1FFFF];
        bool vB = base + 1 < k1, vC = base + 2 < k1, vD = base + 3 < k1;
        edge_math(rA.y, qA.x, qA.y, qA.z, (rA.x >> 17) & (DBN - 1), true, acc, xrl, we0, we1, at);
        edge_math(rB.y, qB.x, qB.y, qB.z, (rB.x >> 17) & (DBN - 1), vB,   acc, xrl, we0, we1, at);
        edge_math(rC.y, qC.x, qC.y, qC.z, (rC.x >> 17) & (DBN - 1), vC,   acc, xrl, we0, we1, at);
        edge_math(rD.y, qD.x, qD.y, qD.z, (rD.x >> 17) & (DBN - 1), vD,   acc, xrl, we0, we1, at);
    }
    __syncthreads();

    float* dst = partG + (size_t)blockIdx.x * ACCW;
    for (int i = threadIdx.x; i < ACCW; i += 256) dst[i] = acc[0][i];
}

template <int LAYER, int QSL>
__global__ __launch_bounds__(512)
void merge_finalize(const float* __restrict__ partG, const float* __restrict__ biasg,
                    const float* __restrict__ x0, const float* __restrict__ x1n0,
                    const float* __restrict__ x2,
                    float* __restrict__ h, double* __restrict__ part) {
    __shared__ double shd[16];
    int b = blockIdx.x;
    int nb0 = b << DBSH;
    int nl = threadIdx.x;
    int cnt = min(DBN, NN - nb0);
    double s1 = 0.0, s2 = 0.0;
    if (nl < cnt) {
        size_t n = nb0 + nl;
        const float* pa = partG + (size_t)b * QSL * ACCW;
        float a[7];
        #pragma unroll
        for (int f = 0; f < 7; ++f) {
            float v = 0.f;
            #pragma unroll
            for (int q = 0; q < QSL; ++q) v += pa[q * ACCW + f * DBN + nl];
            a[f] = v;
        }
        float inv = a[6] != 0.f ? 1.f / a[6] : 0.f;
        #pragma unroll
        for (int f = 0; f < FF; ++f) {
            float t = leakyf(a[f] * inv + biasg[f], 0.01f);
            t += x0[n * FF + f];
            if (LAYER == 1) t += x1n0[n * FF + f] + x2[n * FF + f];
            h[n * FF + f] = t;
            s1 += t;
            s2 += (double)t * (double)t;
        }
    }
    int wid = threadIdx.x >> 6, lane = threadIdx.x & 63;
    #pragma unroll
    for (int o = 32; o > 0; o >>= 1) {
        s1 += __shfl_down(s1, o, 64);
        s2 += __shfl_down(s2, o, 64);
    }
    if (lane == 0) { shd[wid * 2] = s1; shd[wid * 2 + 1] = s2; }
    __syncthreads();
    if (threadIdx.x == 0) {
        double t1 = 0.0, t2 = 0.0;
        #pragma unroll
        for (int w = 0; w < 8; ++w) { t1 += shd[w * 2]; t2 += shd[w * 2 + 1]; }
        part[b * 2 + 0] = t1;
        part[b * 2 + 1] = t2;
    }
}

// ---------- FFN ----------
template <int LAYER>
__global__ __launch_bounds__(NODE_BLOCK)
void node_ffn(const float* __restrict__ h, const double* __restrict__ Snorm,
              const float* __restrict__ f1W, const float* __restrict__ f1b,
              const float* __restrict__ f2W, const float* __restrict__ f2b,
              const float* __restrict__ x0, const float* __restrict__ x1n0_in,
              const float* __restrict__ x2,
              float* __restrict__ x1n0_out, float* __restrict__ gout,
              double* __restrict__ part,
              const float* __restrict__ head, float* __restrict__ dout) {
    __shared__ double sh[8];
    int n = blockIdx.x * blockDim.x + threadIdx.x;
    double s1 = 0.0, s2 = 0.0;
    if (n < NN) {
        float mu, istd;
        norm_params(Snorm, mu, istd);
        float xn[FF];
        #pragma unroll
        for (int f = 0; f < FF; ++f) xn[f] = (h[n * FF + f] - mu) * istd;

        float u[FF], w[FF];
        #pragma unroll
        for (int j = 0; j < FF; ++j) u[j] = f1b[j];
        #pragma unroll
        for (int k = 0; k < FF; ++k) {
            float vk = xn[k];
            #pragma unroll
            for (int j = 0; j < FF; ++j) u[j] = fmaf(vk, f1W[k * FF + j], u[j]);
        }
        #pragma unroll
        for (int j = 0; j < FF; ++j) u[j] = leakyf(u[j], 0.01f);
        #pragma unroll
        for (int j = 0; j < FF; ++j) w[j] = f2b[j];
        #pragma unroll
        for (int k = 0; k < FF; ++k) {
            float vk = u[k];
            #pragma unroll
            for (int j = 0; j < FF; ++j) w[j] = fmaf(vk, f2W[k * FF + j], w[j]);
        }
        #pragma unroll
        for (int f = 0; f < FF; ++f) {
            w[f] += xn[f] + x0[n * FF + f];
            if (LAYER == 1) w[f] += x2[n * FF + f] + x1n0_in[n * FF + f];
        }
        if (LAYER == 0) {
            #pragma unroll
            for (int f = 0; f < FF; ++f) {
                x1n0_out[n * FF + f] = xn[f];
                gout[n * FF + f]     = w[f];
                s1 += w[f];
                s2 += (double)w[f] * (double)w[f];
            }
        } else {
            float o1 = head[6], o2 = head[14];
            #pragma unroll
            for (int f = 0; f < FF; ++f) {
                o1 = fmaf(w[f], head[f], o1);
                o2 = fmaf(w[f], head[8 + f], o2);
            }
            dout[n * 2 + 0] = o1;
            dout[n * 2 + 1] = o2;
        }
    }
    if (LAYER == 0) {
        int wid = threadIdx.x >> 6, lane = threadIdx.x & 63;
        #pragma unroll
        for (int o = 32; o > 0; o >>= 1) {
            s1 += __shfl_down(s1, o, 64);
            s2 += __shfl_down(s2, o, 64);
        }
        if (lane == 0) { sh[wid * 2] = s1; sh[wid * 2 + 1] = s2; }
        __syncthreads();
        if (threadIdx.x == 0) {
            part[blockIdx.x * 2 + 0] = sh[0] + sh[2] + sh[4] + sh[6];
            part[blockIdx.x * 2 + 1] = sh[1] + sh[3] + sh[5] + sh[7];
        }
    }
}

// ---------------------------------------------------------------

extern "C" void kernel_launch(void* const* d_in, const int* in_sizes, int n_in,
                              void* d_out, int out_size, void* d_ws, size_t ws_size,
                              hipStream_t stream) {
    const float* x     = (const float*)d_in[0];
    const float* eattr = (const float*)d_in[1];
    const float* Wl    = (const float*)d_in[2];
    const float* bl    = (const float*)d_in[3];
    const float* Wr    = (const float*)d_in[4];
    const float* br    = (const float*)d_in[5];
    const float* We    = (const float*)d_in[6];
    const float* att   = (const float*)d_in[7];
    const float* biasg = (const float*)d_in[8];
    const float* ff1W  = (const float*)d_in[9];
    const float* ff1b  = (const float*)d_in[10];
    const float* ff2W  = (const float*)d_in[11];
    const float* ff2b  = (const float*)d_in[12];
    const float* Wresh = (const float*)d_in[13];
    const float* bresh = (const float*)d_in[14];
    const float* W1    = (const float*)d_in[15];
    const float* b1    = (const float*)d_in[16];
    const float* W2    = (const float*)d_in[17];
    const float* b2    = (const float*)d_in[18];
    const int*   ei    = (const int*)d_in[19];
    float* out = (float*)d_out;

    char* p = (char*)d_ws;
    auto alloc = [&](size_t bytes) -> char* {
        char* r = p;
        p += (bytes + 255) & ~size_t(255);
        return r;
    };

    // ---- common prefix ----
    double*   S        = (double*)alloc(8 * sizeof(double));
    float*    head     = (float*)alloc(16 * sizeof(float));
    double*   partMA   = (double*)alloc((size_t)NBDST * GNPB * 2 * sizeof(double));  // 401 KB
    double*   partMB   = (double*)alloc((size_t)NBDST * GNPB * 2 * sizeof(double));
    double*   partF    = (double*)alloc((size_t)NODE_GRID * 2 * sizeof(double));
    uv4*      xlb      = (uv4*)alloc((size_t)NN * sizeof(uv4));
    uv4*      xrb      = (uv4*)alloc((size_t)NN * sizeof(uv4));
    float*    h        = (float*)alloc((size_t)NN * FF * sizeof(float));
    float*    x1n0     = (float*)alloc((size_t)NN * FF * sizeof(float));
    float*    x2       = (float*)alloc((size_t)NN * FF * sizeof(float));
    float*    g        = (float*)alloc((size_t)NN * FF * sizeof(float));
    unsigned* cntA     = (unsigned*)alloc((size_t)NBLK * NSB * sizeof(unsigned));
    unsigned* totA     = (unsigned*)alloc((size_t)NSB * sizeof(unsigned));
    int*      segStart = (int*)alloc((size_t)(NSB + 1) * sizeof(int));
    unsigned* cntB     = (unsigned*)alloc((size_t)NBLK * NBDST * sizeof(unsigned));
    unsigned* totB     = (unsigned*)alloc((size_t)NBDST * sizeof(unsigned));
    int*      bstart   = (int*)alloc((size_t)(NBDST + 1) * sizeof(int));
    uv2*      kv       = (uv2*)alloc((size_t)EE * sizeof(uv2));              // 51.2 MB
    unsigned char* bk  = (unsigned char*)alloc((size_t)EE);                  // 6.4 MB
    char* tail = p;
    // ---- fast-path tail ----
    unsigned* cntC     = (unsigned*)alloc((size_t)NBDST * PSEG * DBN * sizeof(unsigned)); // 3.2 MB
    int*      nstart   = (int*)alloc(((size_t)(NBDST << DBSH) + 1) * sizeof(int));        // 402 KB
    unsigned short* recsDs = (unsigned short*)alloc((size_t)EE * 2);         // 12.8 MB
    uv4*      recsAs   = (uv4*)alloc((size_t)EE * sizeof(uv4));              // 102.4 MB
    size_t used = (size_t)(p - (char*)d_ws);
    size_t remain = (ws_size > used) ? (ws_size - used) : 0;
    // pick smallest NG whose ping buffer fits
    int NG = 0;
    {
        const int cands[4] = {1, 2, 4, 8};
        for (int ci = 0; ci < 4; ++ci) {
            int c = cands[ci];
            int maxspan = (NBDST + c - 1) / c;
            size_t Hrec = (size_t)EE * maxspan / NBDST + 32768;
            if (Hrec * sizeof(uv4) <= remain) { NG = c; break; }
        }
    }
    uv4* recsAdH = (uv4*)p;                     // ping buffer (fast path only)
    bool fast = NG > 0;
    // ---- fallback tail (overlaps fast tail; kv overlaid for partG) ----
    uv2*   recsFb  = (uv2*)tail;
    float* partGfb = (float*)kv;

    head_prep<<<1, 64, 0, stream>>>(Wresh, bresh, W1, b1, W2, b2, head, S);

    // ---- graph-only build ----
    hist_src<<<NBLK, 256, 0, stream>>>(ei, cntA);
    scan_bins<NSB><<<NSB, 1024, 0, stream>>>(cntA, totA);
    scan_totals<<<1, 1024, 0, stream>>>(totA, segStart, NSB);
    scatter_src<<<NBLK, 512, 0, stream>>>(ei, eattr, cntA, segStart, kv, bk);
    hist_dst<<<NBLK, 256, 0, stream>>>(bk, cntB);
    scan_bins<NBDST><<<NBDST, 1024, 0, stream>>>(cntB, totB);
    scan_totals<<<1, 1024, 0, stream>>>(totB, bstart, NBDST);

    if (fast) {
        // ---- layer 0 ----
        node_transform<0><<<NODE_GRID, NODE_BLOCK, 0, stream>>>(
            x, nullptr, Wl, bl, Wr, br, xlb, xrb, nullptr);
        scatter_dst_att<<<NBLK, 512, 0, stream>>>(
            kv, bk, cntB, bstart, segStart, xlb, recsAs, recsDs);
        hist_dl<<<NBDST * PSEG, 256, 0, stream>>>(recsDs, bstart, cntC);
        scan_dl<<<NBDST, 512, 0, stream>>>(cntC, bstart, nstart);
        for (int gi = 0; gi < NG; ++gi) {
            int gb = NBDST * gi / NG, ge = NBDST * (gi + 1) / NG;
            permute_rec<<<(ge - gb) * PSEG, 512, 0, stream>>>(
                recsAs, recsDs, cntC, bstart, recsAdH, gb);
            gather_node<0><<<(ge - gb) * GNPB, 256, 0, stream>>>(
                nstart, recsAdH, xrb, We, att, biasg, x, nullptr, nullptr,
                h, partMA, bstart, gb);
        }
        finish_norm<<<1, 256, 0, stream>>>(partMA, NBDST * GNPB, S + 0);
        node_ffn<0><<<NODE_GRID, NODE_BLOCK, 0, stream>>>(
            h, S + 0, ff1W, ff1b, ff2W, ff2b, x, nullptr, nullptr,
            x1n0, g, partF, nullptr, nullptr);
        finish_norm<<<1, 256, 0, stream>>>(partF, NODE_GRID, S + 2);

        // ---- layer 1 ----
        node_transform<1><<<NODE_GRID, NODE_BLOCK, 0, stream>>>(
            g, S + 2, Wl + 36, bl + 6, Wr + 36, br + 6, xlb, xrb, x2);
        scatter_dst_att<<<NBLK, 512, 0, stream>>>(
            kv, bk, cntB, bstart, segStart, xlb, recsAs, recsDs);
        hist_dl<<<NBDST * PSEG, 256, 0, stream>>>(recsDs, bstart, cntC);
        scan_dl<<<NBDST, 512, 0, stream>>>(cntC, bstart, nstart);
        for (int gi = 0; gi < NG; ++gi) {
            int gb = NBDST * gi / NG, ge = NBDST * (gi + 1) / NG;
            permute_rec<<<(ge - gb) * PSEG, 512, 0, stream>>>(
                recsAs, recsDs, cntC, bstart, recsAdH, gb);
            gather_node<1><<<(ge - gb) * GNPB, 256, 0, stream>>>(
                nstart, recsAdH, xrb, We + 12, att + 6, biasg + 6, x, x1n0, x2,
                h, partMB, bstart, gb);
        }
        finish_norm<<<1, 256, 0, stream>>>(partMB, NBDST * GNPB, S + 4);
        node_ffn<1><<<NODE_GRID, NODE_BLOCK, 0, stream>>>(
            h, S + 4, ff1W + 36, ff1b + 6, ff2W + 36, ff2b + 6, x, x1n0, x2,
            nullptr, nullptr, nullptr, head, out);
    } else {
        // ---- fallback: R12 structure ----
        scatter_dst<<<NBLK, 512, 0, stream>>>(kv, bk, cntB, bstart, recsFb);

        node_transform<0><<<NODE_GRID, NODE_BLOCK, 0, stream>>>(
            x, nullptr, Wl, bl, Wr, br, xlb, xrb, nullptr);
        gat_gather_div<QSD><<<NBDST * QSD, 256, 0, stream>>>(
            bstart, recsFb, xlb, xrb, We, att, partGfb);
        merge_finalize<0, QSD><<<NBDST, 512, 0, stream>>>(
            partGfb, biasg, x, nullptr, nullptr, h, partMA);
        finish_norm<<<1, 256, 0, stream>>>(partMA, NBDST, S + 0);
        node_ffn<0><<<NODE_GRID, NODE_BLOCK, 0, stream>>>(
            h, S + 0, ff1W, ff1b, ff2W, ff2b, x, nullptr, nullptr,
            x1n0, g, partF, nullptr, nullptr);
        finish_norm<<<1, 256, 0, stream>>>(partF, NODE_GRID, S + 2);

        node_transform<1><<<NODE_GRID, NODE_BLOCK, 0, stream>>>(
            g, S + 2, Wl + 36, bl + 6, Wr + 36, br + 6, xlb, xrb, x2);
        gat_gather_div<QSD><<<NBDST * QSD, 256, 0, stream>>>(
            bstart, recsFb, xlb, xrb, We + 12, att + 6, partGfb);
        merge_finalize<1, QSD><<<NBDST, 512, 0, stream>>>(
            partGfb, biasg + 6, x, x1n0, x2, h, partMB);
        finish_norm<<<1, 256, 0, stream>>>(partMB, NBDST, S + 4);
        node_ffn<1><<<NODE_GRID, NODE_BLOCK, 0, stream>>>(
            h, S + 4, ff1W + 36, ff1b + 6, ff2W + 36, ff2b + 6, x, x1n0, x2,
            nullptr, nullptr, nullptr, head, out);
    }
}

// Round 16
// 418.902 us; speedup vs baseline: 1.6274x; 1.6274x over previous
//
#include <hip/hip_runtime.h>
#include <math.h>

// Problem constants (from reference)
constexpr int NN = 100000;          // nodes
constexpr int EE = 6400000;         // edges
constexpr int FF = 6;               // features
constexpr int RG = 500;             // reg head hidden
constexpr double MM = 600000.0;     // N*F elements for global norm

constexpr int NODE_BLOCK = 256;
constexpr int NODE_GRID  = (NN + NODE_BLOCK - 1) / NODE_BLOCK;   // 391

constexpr int CHUNK = 8192;
constexpr int NBLK  = (EE + CHUNK - 1) / CHUNK;  // 782
constexpr int SUB   = 4096;                      // pass-A LDS sort sub-batch
constexpr int NSUBB = CHUNK / SUB;               // 2
constexpr int SUBA  = 1024;                      // attach sub-batch
constexpr int NSUBA = CHUNK / SUBA;              // 8
constexpr int SBSH  = 9;                         // src window = 512 nodes
constexpr int NSB   = (NN + (1 << SBSH) - 1) >> SBSH;   // 196
constexpr int DBSH  = 9;                         // dst bucket = 512 nodes
constexpr int DBN   = 1 << DBSH;                 // 512
constexpr int NBDST = (NN + DBN - 1) >> DBSH;    // 196
constexpr int PSEG  = 4;                         // segments per bucket (sort_reduce)
constexpr int SPASS = 2048;                      // records per LDS pass
constexpr int QSD   = 10;                        // fallback gather slices
constexpr int ACCW  = 7 * DBN;                   // partial width (3584 floats)

typedef unsigned uv2 __attribute__((ext_vector_type(2)));
typedef unsigned uv4 __attribute__((ext_vector_type(4)));
typedef float    fv2 __attribute__((ext_vector_type(2)));

__device__ __forceinline__ float leakyf(float v, float s) { return v >= 0.f ? v : s * v; }

__device__ __forceinline__ unsigned f2bf(float x) {   // RNE f32 -> bf16 bits
    unsigned u = __float_as_uint(x);
    return (u + 0x7FFFu + ((u >> 16) & 1u)) >> 16;
}

__device__ __forceinline__ void norm_params(const double* __restrict__ S, float& mu, float& istd) {
    double s1 = S[0], s2 = S[1];
    double mean = s1 / MM;
    double var  = (s2 - s1 * mean) / (MM - 1.0);
    mu   = (float)mean;
    istd = (float)(1.0 / sqrt(var));
}

// K0: collapse regression head; zero norm scalars.
__global__ void head_prep(const float* __restrict__ Wresh, const float* __restrict__ bresh,
                          const float* __restrict__ W1, const float* __restrict__ b1,
                          const float* __restrict__ W2, const float* __restrict__ b2,
                          float* __restrict__ head, double* __restrict__ S) {
    int t = threadIdx.x;
    if (t < 8) S[t] = 0.0;
    if (t < FF) {
        float a1 = 0.f, a2 = 0.f;
        for (int g = 0; g < RG; ++g) {
            float w = Wresh[t * RG + g];
            a1 = fmaf(w, W1[g], a1);
            a2 = fmaf(w, W2[g], a2);
        }
        head[t]     = a1;
        head[8 + t] = a2;
    } else if (t == FF) {
        float a1 = 0.f, a2 = 0.f;
        for (int g = 0; g < RG; ++g) {
            a1 = fmaf(bresh[g], W1[g], a1);
            a2 = fmaf(bresh[g], W2[g], a2);
        }
        head[6]  = a1 + b1[0];
        head[14] = a2 + b2[0];
    }
}

__global__ __launch_bounds__(256)
void finish_norm(const double* __restrict__ part, int cnt, double* __restrict__ S) {
    __shared__ double sh[8];
    int wid = threadIdx.x >> 6, lane = threadIdx.x & 63;
    double s1 = 0.0, s2 = 0.0;
    for (int i = threadIdx.x; i < cnt; i += 256) {
        s1 += part[2 * i];
        s2 += part[2 * i + 1];
    }
    #pragma unroll
    for (int o = 32; o > 0; o >>= 1) {
        s1 += __shfl_down(s1, o, 64);
        s2 += __shfl_down(s2, o, 64);
    }
    if (lane == 0) { sh[wid * 2] = s1; sh[wid * 2 + 1] = s2; }
    __syncthreads();
    if (threadIdx.x == 0) {
        S[0] = sh[0] + sh[2] + sh[4] + sh[6];
        S[1] = sh[1] + sh[3] + sh[5] + sh[7];
    }
}

// ---------- pass A: bin by src-window ----------

__global__ __launch_bounds__(256)
void hist_src(const int* __restrict__ ei, unsigned* __restrict__ cntA) {
    __shared__ unsigned hist[NSB];
    for (int b = threadIdx.x; b < NSB; b += 256) hist[b] = 0u;
    __syncthreads();
    int e0 = blockIdx.x * CHUNK;
    for (int i = threadIdx.x; i < CHUNK; i += 256) {
        int e = e0 + i;
        if (e < EE) {
            int s = __builtin_nontemporal_load(ei + e) % NN;
            atomicAdd(&hist[s >> SBSH], 1u);
        }
    }
    __syncthreads();
    for (int b = threadIdx.x; b < NSB; b += 256)
        cntA[(size_t)blockIdx.x * NSB + b] = hist[b];
}

template <int NBINS>
__global__ __launch_bounds__(1024)
void scan_bins(unsigned* __restrict__ cnt, unsigned* __restrict__ tot) {
    __shared__ unsigned ls[1024];
    int b = blockIdx.x, t = threadIdx.x;
    unsigned v = (t < NBLK) ? cnt[(size_t)t * NBINS + b] : 0u;
    ls[t] = v;
    __syncthreads();
    for (int o = 1; o < 1024; o <<= 1) {
        unsigned add = (t >= o) ? ls[t - o] : 0u;
        __syncthreads();
        ls[t] += add;
        __syncthreads();
    }
    if (t < NBLK) cnt[(size_t)t * NBINS + b] = ls[t] - v;
    if (t == 1023) tot[b] = ls[1023];
}

__global__ __launch_bounds__(1024)
void scan_totals(const unsigned* __restrict__ tot, int* __restrict__ start, int n) {
    __shared__ unsigned ls[1024];
    int t = threadIdx.x;
    unsigned v = (t < n) ? tot[t] : 0u;
    ls[t] = v;
    __syncthreads();
    for (int o = 1; o < 1024; o <<= 1) {
        unsigned add = (t >= o) ? ls[t - o] : 0u;
        __syncthreads();
        ls[t] += add;
        __syncthreads();
    }
    if (t < n) start[t] = (int)(ls[t] - v);
    if (t == 1023) start[n] = (int)ls[1023];
}

// pass A scatter: SoA kv = {src | dl<<17, ea 2xbf16} (8B), bk = dst bucket (1B)
__global__ __launch_bounds__(512)
void scatter_src(const int* __restrict__ ei, const float* __restrict__ eattr,
                 const unsigned* __restrict__ cntA, const int* __restrict__ segStart,
                 uv2* __restrict__ kv, unsigned char* __restrict__ bk) {
    __shared__ unsigned cur[NSB];
    __shared__ unsigned hist[NSB];
    __shared__ unsigned scn[256];
    __shared__ uv2 stage[SUB];
    __shared__ unsigned char stageB[SUB];
    int blk = blockIdx.x;
    int tid = threadIdx.x;
    for (int b = tid; b < NSB; b += 512)
        cur[b] = (unsigned)segStart[b] + cntA[(size_t)blk * NSB + b];
    int e0 = blk * CHUNK;
    for (int s = 0; s < NSUBB; ++s) {
        for (int b = tid; b < NSB; b += 512) hist[b] = 0u;
        __syncthreads();
        int sb0 = e0 + s * SUB;
        unsigned rk[8]; uv2 rc[8]; int bn[8]; unsigned char bb[8]; bool val[8];
        #pragma unroll
        for (int j = 0; j < 8; ++j) {
            int e = sb0 + j * 512 + tid;
            val[j] = e < EE;
            int ss = 0, dd = 0;
            fv2 ea; ea.x = 0.f; ea.y = 0.f;
            if (val[j]) {
                ss = __builtin_nontemporal_load(ei + e) % NN;
                dd = __builtin_nontemporal_load(ei + EE + e) % NN;
                ea = __builtin_nontemporal_load(reinterpret_cast<const fv2*>(eattr) + e);
            }
            bn[j] = ss >> SBSH;
            rc[j].x = (unsigned)ss | ((unsigned)(dd & (DBN - 1)) << 17);
            rc[j].y = f2bf(ea.x) | (f2bf(ea.y) << 16);
            bb[j] = (unsigned char)(dd >> DBSH);
            if (val[j]) rk[j] = atomicAdd(&hist[bn[j]], 1u);
        }
        __syncthreads();
        if (tid < 256) scn[tid] = (tid < NSB) ? hist[tid] : 0u;
        __syncthreads();
        for (int o = 1; o < 256; o <<= 1) {
            unsigned add = 0u;
            if (tid < 256 && tid >= o) add = scn[tid - o];
            __syncthreads();
            if (tid < 256) scn[tid] += add;
            __syncthreads();
        }
        #pragma unroll
        for (int j = 0; j < 8; ++j) {
            if (val[j]) {
                unsigned ex = bn[j] ? scn[bn[j] - 1] : 0u;
                stage[ex + rk[j]]  = rc[j];
                stageB[ex + rk[j]] = bb[j];
            }
        }
        __syncthreads();
        int subCnt = (int)scn[NSB - 1];
        for (int i = tid; i < subCnt; i += 512) {
            uv2 r = stage[i];
            unsigned b = (r.x & 0x1FFFFu) >> SBSH;
            unsigned ex = b ? scn[b - 1] : 0u;
            unsigned pos = cur[b] + (unsigned)i - ex;
            kv[pos] = r;
            bk[pos] = stageB[i];
        }
        __syncthreads();
        for (int b = tid; b < NSB; b += 512) cur[b] += hist[b];
        __syncthreads();
    }
}

// ---------- pass B histogram (dst buckets; graph-only) ----------

__global__ __launch_bounds__(256)
void hist_dst(const unsigned char* __restrict__ bk, unsigned* __restrict__ cntB) {
    __shared__ unsigned hist[NBDST];
    for (int b = threadIdx.x; b < NBDST; b += 256) hist[b] = 0u;
    __syncthreads();
    int e0 = blockIdx.x * CHUNK;
    for (int i = threadIdx.x; i < CHUNK; i += 256) {
        int e = e0 + i;
        if (e < EE) atomicAdd(&hist[bk[e]], 1u);
    }
    __syncthreads();
    for (int b = threadIdx.x; b < NBDST; b += 256)
        cntB[(size_t)blockIdx.x * NBDST + b] = hist[b];
}

// ---------- per-layer attach + bucket scatter (R15, proven 77us @2.7TB/s) ----------
__global__ __launch_bounds__(512)
void scatter_dst_att(const uv2* __restrict__ kv, const unsigned char* __restrict__ bk,
                     const unsigned* __restrict__ cntB, const int* __restrict__ bstart,
                     const int* __restrict__ segStart, const uv4* __restrict__ xlb,
                     uv4* __restrict__ recsA, unsigned short* __restrict__ recsD) {
    __shared__ unsigned cur[NBDST];
    __shared__ unsigned hist[NBDST];
    __shared__ unsigned scn[256];
    __shared__ uv4 win[2][DBN];
    __shared__ uv4 stA[SUBA];
    __shared__ unsigned short stD[SUBA];
    __shared__ unsigned char sbin[SUBA];
    __shared__ int w0s;
    int blk = blockIdx.x;
    int tid = threadIdx.x;
    int e0 = blk * CHUNK;
    if (tid == 0) w0s = 0;
    __syncthreads();
    if (tid < NSB && segStart[tid] <= e0 && e0 < segStart[tid + 1]) w0s = tid;
    __syncthreads();
    int w0 = w0s;
    int w1 = min(w0 + 1, NSB - 1);
    for (int i = tid; i < DBN; i += 512) {
        int g0 = (w0 << SBSH) + i;
        int g1 = (w1 << SBSH) + i;
        uv4 z; z.x = 0u; z.y = 0u; z.z = 0u; z.w = 0u;
        win[0][i] = (g0 < NN) ? xlb[g0] : z;
        win[1][i] = (g1 < NN) ? xlb[g1] : z;
    }
    for (int b = tid; b < NBDST; b += 512)
        cur[b] = (unsigned)bstart[b] + cntB[(size_t)blk * NBDST + b];
    __syncthreads();

    for (int s = 0; s < NSUBA; ++s) {
        for (int b = tid; b < NBDST; b += 512) hist[b] = 0u;
        __syncthreads();
        int sb0 = e0 + s * SUBA;
        unsigned rk[2]; uv4 rc[2]; unsigned short dl2[2]; int bn[2]; bool val[2];
        #pragma unroll
        for (int j = 0; j < 2; ++j) {
            int e = sb0 + j * 512 + tid;
            val[j] = e < EE;
            uv2 r; r.x = 0u; r.y = 0u;
            int b = 0;
            if (val[j]) {
                r = __builtin_nontemporal_load(kv + e);
                b = (int)bk[e];
            }
            int src = (int)(r.x & 0x1FFFFu);
            int sel = min(max((src >> SBSH) - w0, 0), 1);
            uv4 q = win[sel][src & (DBN - 1)];
            rc[j].x = r.y;
            rc[j].y = q.x;
            rc[j].z = q.y;
            rc[j].w = q.z;
            dl2[j] = (unsigned short)((r.x >> 17) & (DBN - 1));
            bn[j] = b;
            if (val[j]) rk[j] = atomicAdd(&hist[bn[j]], 1u);
        }
        __syncthreads();
        if (tid < 256) scn[tid] = (tid < NBDST) ? hist[tid] : 0u;
        __syncthreads();
        for (int o = 1; o < 256; o <<= 1) {
            unsigned add = 0u;
            if (tid < 256 && tid >= o) add = scn[tid - o];
            __syncthreads();
            if (tid < 256) scn[tid] += add;
            __syncthreads();
        }
        #pragma unroll
        for (int j = 0; j < 2; ++j) {
            if (val[j]) {
                unsigned ex = bn[j] ? scn[bn[j] - 1] : 0u;
                unsigned p = ex + rk[j];
                stA[p] = rc[j];
                stD[p] = dl2[j];
                sbin[p] = (unsigned char)bn[j];
            }
        }
        __syncthreads();
        int subCnt = (int)scn[NBDST - 1];
        for (int i = tid; i < subCnt; i += 512) {
            unsigned b = sbin[i];
            unsigned ex = b ? scn[b - 1] : 0u;
            unsigned pos = cur[b] + (unsigned)i - ex;
            recsA[pos] = stA[i];
            recsD[pos] = stD[i];
        }
        __syncthreads();
        for (int b = tid; b < NBDST; b += 512) cur[b] += hist[b];
        __syncthreads();
    }
}

// ---------- fused LDS sort + register reduce (zero global atomics, no permuted copy) ----------
// one block per (bucket, seg); thread t owns node (bucket<<9)+t; multi-pass:
// {load 2048 recs, LDS counting sort by dl, thread t reduces its contiguous segment}
__global__ __launch_bounds__(512)
void sort_reduce(const uv4* __restrict__ recsA, const unsigned short* __restrict__ recsD,
                 const int* __restrict__ bstart, const uv4* __restrict__ xrb,
                 const float* __restrict__ Wef, const float* __restrict__ attf,
                 float* __restrict__ partG) {
    __shared__ uv4 stage[SPASS];      // 32 KB
    __shared__ unsigned hist[DBN];    // 2 KB
    __shared__ unsigned scn[DBN];     // 2 KB
    int b = blockIdx.x / PSEG, s = blockIdx.x % PSEG;
    int b0 = bstart[b], b1 = bstart[b + 1], len = b1 - b0;
    int k0 = b0 + (int)(((long long)len * s) / PSEG);
    int k1 = b0 + (int)(((long long)len * (s + 1)) / PSEG);
    int tid = threadIdx.x;

    float we0[FF], we1[FF], at[FF];
    #pragma unroll
    for (int f = 0; f < FF; ++f) { we0[f] = Wef[f]; we1[f] = Wef[FF + f]; at[f] = attf[f]; }
    int n = (b << DBSH) + tid;
    float bv[FF] = {0.f, 0.f, 0.f, 0.f, 0.f, 0.f};
    if (n < NN) {
        uv4 r = xrb[n];
        bv[0] = __uint_as_float(r.x << 16);  bv[1] = __uint_as_float(r.x & 0xFFFF0000u);
        bv[2] = __uint_as_float(r.y << 16);  bv[3] = __uint_as_float(r.y & 0xFFFF0000u);
        bv[4] = __uint_as_float(r.z << 16);  bv[5] = __uint_as_float(r.z & 0xFFFF0000u);
    }
    float acc[7] = {0.f, 0.f, 0.f, 0.f, 0.f, 0.f, 0.f};

    for (int base = k0; base < k1; base += SPASS) {
        hist[tid] = 0u;
        __syncthreads();
        unsigned rk[4]; uv4 rc[4]; int dl[4]; bool val[4];
        #pragma unroll
        for (int j = 0; j < 4; ++j) {
            int k = base + j * 512 + tid;
            val[j] = k < k1;
            uv4 r; r.x = 0u; r.y = 0u; r.z = 0u; r.w = 0u;
            int d = 0;
            if (val[j]) {
                r = __builtin_nontemporal_load(recsA + k);
                d = (int)recsD[k];
            }
            rc[j] = r;
            dl[j] = d;
            if (val[j]) rk[j] = atomicAdd(&hist[d], 1u);
        }
        __syncthreads();
        scn[tid] = hist[tid];
        __syncthreads();
        for (int o = 1; o < DBN; o <<= 1) {
            unsigned add = (tid >= o) ? scn[tid - o] : 0u;
            __syncthreads();
            scn[tid] += add;
            __syncthreads();
        }
        #pragma unroll
        for (int j = 0; j < 4; ++j) {
            if (val[j]) {
                unsigned ex = dl[j] ? scn[dl[j] - 1] : 0u;
                stage[ex + rk[j]] = rc[j];
            }
        }
        __syncthreads();
        // reduce my node's segment (contiguous in stage)
        unsigned e0s = scn[tid] - hist[tid], e1s = scn[tid];
        for (unsigned j = e0s; j < e1s; ++j) {
            uv4 a = stage[j];
            float eax = __uint_as_float(a.x << 16);
            float eay = __uint_as_float(a.x & 0xFFFF0000u);
            float av[FF];
            av[0] = __uint_as_float(a.y << 16);  av[1] = __uint_as_float(a.y & 0xFFFF0000u);
            av[2] = __uint_as_float(a.z << 16);  av[3] = __uint_as_float(a.z & 0xFFFF0000u);
            av[4] = __uint_as_float(a.w << 16);  av[5] = __uint_as_float(a.w & 0xFFFF0000u);
            float logit = 0.f;
            #pragma unroll
            for (int f = 0; f < FF; ++f) {
                float m = av[f] + bv[f] + fmaf(eay, we1[f], eax * we0[f]);
                m = m >= 0.f ? m : 0.2f * m;
                logit = fmaf(at[f], m, logit);
            }
            float w = __expf(logit);
            acc[6] += w;
            #pragma unroll
            for (int f = 0; f < FF; ++f) acc[f] = fmaf(w, av[f], acc[f]);
        }
        __syncthreads();
    }
    float* dst = partG + (size_t)blockIdx.x * ACCW;
    #pragma unroll
    for (int f = 0; f < 7; ++f) dst[f * DBN + tid] = acc[f];
}

// ---------- merge partials + finalize (one block of 512 per bucket) ----------
template <int LAYER, int QSL>
__global__ __launch_bounds__(512)
void merge_finalize(const float* __restrict__ partG, const float* __restrict__ biasg,
                    const float* __restrict__ x0, const float* __restrict__ x1n0,
                    const float* __restrict__ x2,
                    float* __restrict__ h, double* __restrict__ part) {
    __shared__ double shd[16];
    int b = blockIdx.x;
    int nb0 = b << DBSH;
    int nl = threadIdx.x;
    int cnt = min(DBN, NN - nb0);
    double s1 = 0.0, s2 = 0.0;
    if (nl < cnt) {
        size_t n = nb0 + nl;
        const float* pa = partG + (size_t)b * QSL * ACCW;
        float a[7];
        #pragma unroll
        for (int f = 0; f < 7; ++f) {
            float v = 0.f;
            #pragma unroll
            for (int q = 0; q < QSL; ++q) v += pa[q * ACCW + f * DBN + nl];
            a[f] = v;
        }
        float inv = a[6] != 0.f ? 1.f / a[6] : 0.f;
        #pragma unroll
        for (int f = 0; f < FF; ++f) {
            float t = leakyf(a[f] * inv + biasg[f], 0.01f);
            t += x0[n * FF + f];
            if (LAYER == 1) t += x1n0[n * FF + f] + x2[n * FF + f];
            h[n * FF + f] = t;
            s1 += t;
            s2 += (double)t * (double)t;
        }
    }
    int wid = threadIdx.x >> 6, lane = threadIdx.x & 63;
    #pragma unroll
    for (int o = 32; o > 0; o >>= 1) {
        s1 += __shfl_down(s1, o, 64);
        s2 += __shfl_down(s2, o, 64);
    }
    if (lane == 0) { shd[wid * 2] = s1; shd[wid * 2 + 1] = s2; }
    __syncthreads();
    if (threadIdx.x == 0) {
        double t1 = 0.0, t2 = 0.0;
        #pragma unroll
        for (int w = 0; w < 8; ++w) { t1 += shd[w * 2]; t2 += shd[w * 2 + 1]; }
        part[b * 2 + 0] = t1;
        part[b * 2 + 1] = t2;
    }
}

// ---------- node transform: xlb + xrb, both bf16 packed (16B/node) ----------
template <int LAYER>
__global__ __launch_bounds__(NODE_BLOCK)
void node_transform(const float* __restrict__ xin, const double* __restrict__ Snorm,
                    const float* __restrict__ Wl, const float* __restrict__ bl,
                    const float* __restrict__ Wr, const float* __restrict__ br,
                    uv4* __restrict__ xlb, uv4* __restrict__ xrb,
                    float* __restrict__ x2out) {
    int n = blockIdx.x * blockDim.x + threadIdx.x;
    if (n >= NN) return;
    float v[FF];
    if (LAYER == 0) {
        #pragma unroll
        for (int f = 0; f < FF; ++f) v[f] = xin[n * FF + f];
    } else {
        float mu, istd;
        norm_params(Snorm, mu, istd);
        #pragma unroll
        for (int f = 0; f < FF; ++f) {
            v[f] = (xin[n * FF + f] - mu) * istd;
            x2out[n * FF + f] = v[f];
        }
    }
    float ol[FF], orr[FF];
    #pragma unroll
    for (int j = 0; j < FF; ++j) { ol[j] = bl[j]; orr[j] = br[j]; }
    #pragma unroll
    for (int k = 0; k < FF; ++k) {
        float vk = v[k];
        #pragma unroll
        for (int j = 0; j < FF; ++j) {
            ol[j]  = fmaf(vk, Wl[k * FF + j], ol[j]);
            orr[j] = fmaf(vk, Wr[k * FF + j], orr[j]);
        }
    }
    uv4 q;
    q.x = f2bf(ol[0]) | (f2bf(ol[1]) << 16);
    q.y = f2bf(ol[2]) | (f2bf(ol[3]) << 16);
    q.z = f2bf(ol[4]) | (f2bf(ol[5]) << 16);
    q.w = 0u;
    xlb[n] = q;
    uv4 r;
    r.x = f2bf(orr[0]) | (f2bf(orr[1]) << 16);
    r.y = f2bf(orr[2]) | (f2bf(orr[3]) << 16);
    r.z = f2bf(orr[4]) | (f2bf(orr[5]) << 16);
    r.w = 0u;
    xrb[n] = r;
}

// ---------- FALLBACK kernels (R12, proven) ----------
__global__ __launch_bounds__(512)
void scatter_dst(const uv2* __restrict__ kv, const unsigned char* __restrict__ bk,
                 const unsigned* __restrict__ cntB, const int* __restrict__ bstart,
                 uv2* __restrict__ recs) {
    __shared__ unsigned cur[NBDST];
    __shared__ unsigned hist[NBDST];
    __shared__ unsigned scn[256];
    __shared__ uv2 stage[SUB];
    __shared__ unsigned char sbin[SUB];
    int blk = blockIdx.x;
    int tid = threadIdx.x;
    for (int b = tid; b < NBDST; b += 512)
        cur[b] = (unsigned)bstart[b] + cntB[(size_t)blk * NBDST + b];
    int e0 = blk * CHUNK;
    for (int s = 0; s < NSUBB; ++s) {
        for (int b = tid; b < NBDST; b += 512) hist[b] = 0u;
        __syncthreads();
        int sb0 = e0 + s * SUB;
        unsigned rk[8]; uv2 rc[8]; int bn[8]; bool val[8];
        #pragma unroll
        for (int j = 0; j < 8; ++j) {
            int e = sb0 + j * 512 + tid;
            val[j] = e < EE;
            uv2 r; r.x = 0u; r.y = 0u;
            int b = 0;
            if (val[j]) {
                r = __builtin_nontemporal_load(kv + e);
                b = (int)bk[e];
            }
            rc[j] = r;
            bn[j] = b;
            if (val[j]) rk[j] = atomicAdd(&hist[bn[j]], 1u);
        }
        __syncthreads();
        if (tid < 256) scn[tid] = (tid < NBDST) ? hist[tid] : 0u;
        __syncthreads();
        for (int o = 1; o < 256; o <<= 1) {
            unsigned add = 0u;
            if (tid < 256 && tid >= o) add = scn[tid - o];
            __syncthreads();
            if (tid < 256) scn[tid] += add;
            __syncthreads();
        }
        #pragma unroll
        for (int j = 0; j < 8; ++j) {
            if (val[j]) {
                unsigned ex = bn[j] ? scn[bn[j] - 1] : 0u;
                stage[ex + rk[j]] = rc[j];
                sbin[ex + rk[j]] = (unsigned char)bn[j];
            }
        }
        __syncthreads();
        int subCnt = (int)scn[NBDST - 1];
        for (int i = tid; i < subCnt; i += 512) {
            uv2 r = stage[i];
            unsigned b = sbin[i];
            unsigned ex = b ? scn[b - 1] : 0u;
            recs[cur[b] + (unsigned)i - ex] = r;
        }
        __syncthreads();
        for (int b = tid; b < NBDST; b += 512) cur[b] += hist[b];
        __syncthreads();
    }
}

__device__ __forceinline__ void edge_math(unsigned eaw, unsigned a01, unsigned a23, unsigned a45,
                                          int dl, bool valid,
                                          float (&acc)[7][DBN], const uv4* __restrict__ xrl,
                                          const float we0[FF], const float we1[FF],
                                          const float at[FF]) {
    uv4 r = xrl[dl];
    float eax = __uint_as_float(eaw << 16);
    float eay = __uint_as_float(eaw & 0xFFFF0000u);
    float av[FF], bv[FF];
    av[0] = __uint_as_float(a01 << 16);  av[1] = __uint_as_float(a01 & 0xFFFF0000u);
    av[2] = __uint_as_float(a23 << 16);  av[3] = __uint_as_float(a23 & 0xFFFF0000u);
    av[4] = __uint_as_float(a45 << 16);  av[5] = __uint_as_float(a45 & 0xFFFF0000u);
    bv[0] = __uint_as_float(r.x << 16);  bv[1] = __uint_as_float(r.x & 0xFFFF0000u);
    bv[2] = __uint_as_float(r.y << 16);  bv[3] = __uint_as_float(r.y & 0xFFFF0000u);
    bv[4] = __uint_as_float(r.z << 16);  bv[5] = __uint_as_float(r.z & 0xFFFF0000u);
    float logit = 0.f;
    #pragma unroll
    for (int f = 0; f < FF; ++f) {
        float m = av[f] + bv[f] + fmaf(eay, we1[f], eax * we0[f]);
        m = m >= 0.f ? m : 0.2f * m;
        logit = fmaf(at[f], m, logit);
    }
    float w = __expf(logit);
    w = valid ? w : 0.f;
    atomicAdd(&acc[6][dl], w);
    #pragma unroll
    for (int f = 0; f < FF; ++f) atomicAdd(&acc[f][dl], w * av[f]);
}

template <int QSL>
__global__ __launch_bounds__(256)
void gat_gather_div(const int* __restrict__ bucketStart, const uv2* __restrict__ recs,
                    const uv4* __restrict__ xlb, const uv4* __restrict__ xrb,
                    const float* __restrict__ Wef, const float* __restrict__ attf,
                    float* __restrict__ partG) {
    __shared__ float acc[7][DBN];
    __shared__ uv4 xrl[DBN];
    int b  = blockIdx.x / QSL;
    int qq = blockIdx.x % QSL;
    int nb0 = b << DBSH;
    int cnt = min(DBN, NN - nb0);

    for (int i = threadIdx.x; i < 7 * DBN; i += 256) acc[0][i] = 0.f;
    for (int i = threadIdx.x; i < cnt; i += 256) xrl[i] = xrb[nb0 + i];
    float we0[FF], we1[FF], at[FF];
    #pragma unroll
    for (int f = 0; f < FF; ++f) { we0[f] = Wef[f]; we1[f] = Wef[FF + f]; at[f] = attf[f]; }
    __syncthreads();

    int bk0 = bucketStart[b], bk1 = bucketStart[b + 1];
    int len = bk1 - bk0;
    int k0 = bk0 + (int)(((long long)len * qq) / QSL);
    int k1 = bk0 + (int)(((long long)len * (qq + 1)) / QSL);
    int last = k1 - 1;
    for (int base = k0 + threadIdx.x * 4; base < k1; base += 1024) {
        uv2 rA = __builtin_nontemporal_load(recs + base);
        uv2 rB = __builtin_nontemporal_load(recs + min(base + 1, last));
        uv2 rC = __builtin_nontemporal_load(recs + min(base + 2, last));
        uv2 rD = __builtin_nontemporal_load(recs + min(base + 3, last));
        uv4 qA = xlb[rA.x & 0x1FFFF];
        uv4 qB = xlb[rB.x & 0x1FFFF];
        uv4 qC = xlb[rC.x & 0x1FFFF];
        uv4 qD = xlb[rD.x & 0x1FFFF];
        bool vB = base + 1 < k1, vC = base + 2 < k1, vD = base + 3 < k1;
        edge_math(rA.y, qA.x, qA.y, qA.z, (rA.x >> 17) & (DBN - 1), true, acc, xrl, we0, we1, at);
        edge_math(rB.y, qB.x, qB.y, qB.z, (rB.x >> 17) & (DBN - 1), vB,   acc, xrl, we0, we1, at);
        edge_math(rC.y, qC.x, qC.y, qC.z, (rC.x >> 17) & (DBN - 1), vC,   acc, xrl, we0, we1, at);
        edge_math(rD.y, qD.x, qD.y, qD.z, (rD.x >> 17) & (DBN - 1), vD,   acc, xrl, we0, we1, at);
    }
    __syncthreads();

    float* dst = partG + (size_t)blockIdx.x * ACCW;
    for (int i = threadIdx.x; i < ACCW; i += 256) dst[i] = acc[0][i];
}

// ---------- FFN ----------
template <int LAYER>
__global__ __launch_bounds__(NODE_BLOCK)
void node_ffn(const float* __restrict__ h, const double* __restrict__ Snorm,
              const float* __restrict__ f1W, const float* __restrict__ f1b,
              const float* __restrict__ f2W, const float* __restrict__ f2b,
              const float* __restrict__ x0, const float* __restrict__ x1n0_in,
              const float* __restrict__ x2,
              float* __restrict__ x1n0_out, float* __restrict__ gout,
              double* __restrict__ part,
              const float* __restrict__ head, float* __restrict__ dout) {
    __shared__ double sh[8];
    int n = blockIdx.x * blockDim.x + threadIdx.x;
    double s1 = 0.0, s2 = 0.0;
    if (n < NN) {
        float mu, istd;
        norm_params(Snorm, mu, istd);
        float xn[FF];
        #pragma unroll
        for (int f = 0; f < FF; ++f) xn[f] = (h[n * FF + f] - mu) * istd;

        float u[FF], w[FF];
        #pragma unroll
        for (int j = 0; j < FF; ++j) u[j] = f1b[j];
        #pragma unroll
        for (int k = 0; k < FF; ++k) {
            float vk = xn[k];
            #pragma unroll
            for (int j = 0; j < FF; ++j) u[j] = fmaf(vk, f1W[k * FF + j], u[j]);
        }
        #pragma unroll
        for (int j = 0; j < FF; ++j) u[j] = leakyf(u[j], 0.01f);
        #pragma unroll
        for (int j = 0; j < FF; ++j) w[j] = f2b[j];
        #pragma unroll
        for (int k = 0; k < FF; ++k) {
            float vk = u[k];
            #pragma unroll
            for (int j = 0; j < FF; ++j) w[j] = fmaf(vk, f2W[k * FF + j], w[j]);
        }
        #pragma unroll
        for (int f = 0; f < FF; ++f) {
            w[f] += xn[f] + x0[n * FF + f];
            if (LAYER == 1) w[f] += x2[n * FF + f] + x1n0_in[n * FF + f];
        }
        if (LAYER == 0) {
            #pragma unroll
            for (int f = 0; f < FF; ++f) {
                x1n0_out[n * FF + f] = xn[f];
                gout[n * FF + f]     = w[f];
                s1 += w[f];
                s2 += (double)w[f] * (double)w[f];
            }
        } else {
            float o1 = head[6], o2 = head[14];
            #pragma unroll
            for (int f = 0; f < FF; ++f) {
                o1 = fmaf(w[f], head[f], o1);
                o2 = fmaf(w[f], head[8 + f], o2);
            }
            dout[n * 2 + 0] = o1;
            dout[n * 2 + 1] = o2;
        }
    }
    if (LAYER == 0) {
        int wid = threadIdx.x >> 6, lane = threadIdx.x & 63;
        #pragma unroll
        for (int o = 32; o > 0; o >>= 1) {
            s1 += __shfl_down(s1, o, 64);
            s2 += __shfl_down(s2, o, 64);
        }
        if (lane == 0) { sh[wid * 2] = s1; sh[wid * 2 + 1] = s2; }
        __syncthreads();
        if (threadIdx.x == 0) {
            part[blockIdx.x * 2 + 0] = sh[0] + sh[2] + sh[4] + sh[6];
            part[blockIdx.x * 2 + 1] = sh[1] + sh[3] + sh[5] + sh[7];
        }
    }
}

// ---------------------------------------------------------------

extern "C" void kernel_launch(void* const* d_in, const int* in_sizes, int n_in,
                              void* d_out, int out_size, void* d_ws, size_t ws_size,
                              hipStream_t stream) {
    const float* x     = (const float*)d_in[0];
    const float* eattr = (const float*)d_in[1];
    const float* Wl    = (const float*)d_in[2];
    const float* bl    = (const float*)d_in[3];
    const float* Wr    = (const float*)d_in[4];
    const float* br    = (const float*)d_in[5];
    const float* We    = (const float*)d_in[6];
    const float* att   = (const float*)d_in[7];
    const float* biasg = (const float*)d_in[8];
    const float* ff1W  = (const float*)d_in[9];
    const float* ff1b  = (const float*)d_in[10];
    const float* ff2W  = (const float*)d_in[11];
    const float* ff2b  = (const float*)d_in[12];
    const float* Wresh = (const float*)d_in[13];
    const float* bresh = (const float*)d_in[14];
    const float* W1    = (const float*)d_in[15];
    const float* b1    = (const float*)d_in[16];
    const float* W2    = (const float*)d_in[17];
    const float* b2    = (const float*)d_in[18];
    const int*   ei    = (const int*)d_in[19];
    float* out = (float*)d_out;

    char* p = (char*)d_ws;
    auto alloc = [&](size_t bytes) -> char* {
        char* r = p;
        p += (bytes + 255) & ~size_t(255);
        return r;
    };

    // ---- common prefix ----
    double*   S        = (double*)alloc(8 * sizeof(double));
    float*    head     = (float*)alloc(16 * sizeof(float));
    double*   partMA   = (double*)alloc((size_t)NBDST * 2 * sizeof(double));
    double*   partMB   = (double*)alloc((size_t)NBDST * 2 * sizeof(double));
    double*   partF    = (double*)alloc((size_t)NODE_GRID * 2 * sizeof(double));
    uv4*      xlb      = (uv4*)alloc((size_t)NN * sizeof(uv4));
    uv4*      xrb      = (uv4*)alloc((size_t)NN * sizeof(uv4));
    float*    h        = (float*)alloc((size_t)NN * FF * sizeof(float));
    float*    x1n0     = (float*)alloc((size_t)NN * FF * sizeof(float));
    float*    x2       = (float*)alloc((size_t)NN * FF * sizeof(float));
    float*    g        = (float*)alloc((size_t)NN * FF * sizeof(float));
    unsigned* cntA     = (unsigned*)alloc((size_t)NBLK * NSB * sizeof(unsigned));
    unsigned* totA     = (unsigned*)alloc((size_t)NSB * sizeof(unsigned));
    int*      segStart = (int*)alloc((size_t)(NSB + 1) * sizeof(int));
    unsigned* cntB     = (unsigned*)alloc((size_t)NBLK * NBDST * sizeof(unsigned));
    unsigned* totB     = (unsigned*)alloc((size_t)NBDST * sizeof(unsigned));
    int*      bstart   = (int*)alloc((size_t)(NBDST + 1) * sizeof(int));
    uv2*      kv       = (uv2*)alloc((size_t)EE * sizeof(uv2));              // 51.2 MB
    unsigned char* bk  = (unsigned char*)alloc((size_t)EE);                  // 6.4 MB
    char* tail = p;
    // ---- fast-path tail (~126.5 MB; total ~198 MB < proven 209 MB floor) ----
    unsigned short* recsDs = (unsigned short*)alloc((size_t)EE * 2);         // 12.8 MB
    uv4*      recsAs   = (uv4*)alloc((size_t)EE * sizeof(uv4));              // 102.4 MB
    float*    partG    = (float*)alloc((size_t)NBDST * PSEG * ACCW * sizeof(float)); // 11.2 MB
    size_t need_fast = (size_t)(p - (char*)d_ws);
    bool fast = need_fast <= ws_size;
    // ---- fallback tail (overlaps fast tail; kv overlaid for partG) ----
    uv2*   recsFb  = (uv2*)tail;
    float* partGfb = (float*)kv;

    head_prep<<<1, 64, 0, stream>>>(Wresh, bresh, W1, b1, W2, b2, head, S);

    // ---- graph-only build ----
    hist_src<<<NBLK, 256, 0, stream>>>(ei, cntA);
    scan_bins<NSB><<<NSB, 1024, 0, stream>>>(cntA, totA);
    scan_totals<<<1, 1024, 0, stream>>>(totA, segStart, NSB);
    scatter_src<<<NBLK, 512, 0, stream>>>(ei, eattr, cntA, segStart, kv, bk);
    hist_dst<<<NBLK, 256, 0, stream>>>(bk, cntB);
    scan_bins<NBDST><<<NBDST, 1024, 0, stream>>>(cntB, totB);
    scan_totals<<<1, 1024, 0, stream>>>(totB, bstart, NBDST);

    if (fast) {
        // ---- layer 0 ----
        node_transform<0><<<NODE_GRID, NODE_BLOCK, 0, stream>>>(
            x, nullptr, Wl, bl, Wr, br, xlb, xrb, nullptr);
        scatter_dst_att<<<NBLK, 512, 0, stream>>>(
            kv, bk, cntB, bstart, segStart, xlb, recsAs, recsDs);
        sort_reduce<<<NBDST * PSEG, 512, 0, stream>>>(
            recsAs, recsDs, bstart, xrb, We, att, partG);
        merge_finalize<0, PSEG><<<NBDST, 512, 0, stream>>>(
            partG, biasg, x, nullptr, nullptr, h, partMA);
        finish_norm<<<1, 256, 0, stream>>>(partMA, NBDST, S + 0);
        node_ffn<0><<<NODE_GRID, NODE_BLOCK, 0, stream>>>(
            h, S + 0, ff1W, ff1b, ff2W, ff2b, x, nullptr, nullptr,
            x1n0, g, partF, nullptr, nullptr);
        finish_norm<<<1, 256, 0, stream>>>(partF, NODE_GRID, S + 2);

        // ---- layer 1 ----
        node_transform<1><<<NODE_GRID, NODE_BLOCK, 0, stream>>>(
            g, S + 2, Wl + 36, bl + 6, Wr + 36, br + 6, xlb, xrb, x2);
        scatter_dst_att<<<NBLK, 512, 0, stream>>>(
            kv, bk, cntB, bstart, segStart, xlb, recsAs, recsDs);
        sort_reduce<<<NBDST * PSEG, 512, 0, stream>>>(
            recsAs, recsDs, bstart, xrb, We + 12, att + 6, partG);
        merge_finalize<1, PSEG><<<NBDST, 512, 0, stream>>>(
            partG, biasg + 6, x, x1n0, x2, h, partMB);
        finish_norm<<<1, 256, 0, stream>>>(partMB, NBDST, S + 4);
        node_ffn<1><<<NODE_GRID, NODE_BLOCK, 0, stream>>>(
            h, S + 4, ff1W + 36, ff1b + 6, ff2W + 36, ff2b + 6, x, x1n0, x2,
            nullptr, nullptr, nullptr, head, out);
    } else {
        // ---- fallback: R12 structure ----
        scatter_dst<<<NBLK, 512, 0, stream>>>(kv, bk, cntB, bstart, recsFb);

        node_transform<0><<<NODE_GRID, NODE_BLOCK, 0, stream>>>(
            x, nullptr, Wl, bl, Wr, br, xlb, xrb, nullptr);
        gat_gather_div<QSD><<<NBDST * QSD, 256, 0, stream>>>(
            bstart, recsFb, xlb, xrb, We, att, partGfb);
        merge_finalize<0, QSD><<<NBDST, 512, 0, stream>>>(
            partGfb, biasg, x, nullptr, nullptr, h, partMA);
        finish_norm<<<1, 256, 0, stream>>>(partMA, NBDST, S + 0);
        node_ffn<0><<<NODE_GRID, NODE_BLOCK, 0, stream>>>(
            h, S + 0, ff1W, ff1b, ff2W, ff2b, x, nullptr, nullptr,
            x1n0, g, partF, nullptr, nullptr);
        finish_norm<<<1, 256, 0, stream>>>(partF, NODE_GRID, S + 2);

        node_transform<1><<<NODE_GRID, NODE_BLOCK, 0, stream>>>(
            g, S + 2, Wl + 36, bl + 6, Wr + 36, br + 6, xlb, xrb, x2);
        gat_gather_div<QSD><<<NBDST * QSD, 256, 0, stream>>>(
            bstart, recsFb, xlb, xrb, We + 12, att + 6, partGfb);
        merge_finalize<1, QSD><<<NBDST, 512, 0, stream>>>(
            partGfb, biasg + 6, x, x1n0, x2, h, partMB);
        finish_norm<<<1, 256, 0, stream>>>(partMB, NBDST, S + 4);
        node_ffn<1><<<NODE_GRID, NODE_BLOCK, 0, stream>>>(
            h, S + 4, ff1W + 36, ff1b + 6, ff2W + 36, ff2b + 6, x, x1n0, x2,
            nullptr, nullptr, nullptr, head, out);
    }
}

// Round 17
// 401.445 us; speedup vs baseline: 1.6982x; 1.0435x over previous
//
#include <hip/hip_runtime.h>
#include <math.h>

// Problem constants (from reference)
constexpr int NN = 100000;          // nodes
constexpr int EE = 6400000;         // edges
constexpr int FF = 6;               // features
constexpr int RG = 500;             // reg head hidden
constexpr double MM = 600000.0;     // N*F elements for global norm

constexpr int NODE_BLOCK = 256;
constexpr int NODE_GRID  = (NN + NODE_BLOCK - 1) / NODE_BLOCK;   // 391

constexpr int CHUNK = 8192;
constexpr int NBLK  = (EE + CHUNK - 1) / CHUNK;  // 782
constexpr int SUB   = 4096;                      // pass-A LDS sort sub-batch
constexpr int NSUBB = CHUNK / SUB;               // 2
constexpr int SUBA  = 2048;                      // attach sub-batch (R17: 1024->2048)
constexpr int NSUBA = CHUNK / SUBA;              // 4
constexpr int SBSH  = 9;                         // src window = 512 nodes
constexpr int NSB   = (NN + (1 << SBSH) - 1) >> SBSH;   // 196
constexpr int DBSH  = 9;                         // dst bucket = 512 nodes
constexpr int DBN   = 1 << DBSH;                 // 512
constexpr int NBDST = (NN + DBN - 1) >> DBSH;    // 196
constexpr int PSEG  = 4;                         // segments per bucket (sort_reduce)
constexpr int SPASS = 2048;                      // records per LDS pass
constexpr int QSD   = 10;                        // fallback gather slices
constexpr int ACCW  = 7 * DBN;                   // partial width (3584 floats)

typedef unsigned uv2 __attribute__((ext_vector_type(2)));
typedef unsigned uv4 __attribute__((ext_vector_type(4)));
typedef float    fv2 __attribute__((ext_vector_type(2)));

__device__ __forceinline__ float leakyf(float v, float s) { return v >= 0.f ? v : s * v; }

__device__ __forceinline__ unsigned f2bf(float x) {   // RNE f32 -> bf16 bits
    unsigned u = __float_as_uint(x);
    return (u + 0x7FFFu + ((u >> 16) & 1u)) >> 16;
}

__device__ __forceinline__ void norm_params(const double* __restrict__ S, float& mu, float& istd) {
    double s1 = S[0], s2 = S[1];
    double mean = s1 / MM;
    double var  = (s2 - s1 * mean) / (MM - 1.0);
    mu   = (float)mean;
    istd = (float)(1.0 / sqrt(var));
}

// K0: collapse regression head; zero norm scalars.
__global__ void head_prep(const float* __restrict__ Wresh, const float* __restrict__ bresh,
                          const float* __restrict__ W1, const float* __restrict__ b1,
                          const float* __restrict__ W2, const float* __restrict__ b2,
                          float* __restrict__ head, double* __restrict__ S) {
    int t = threadIdx.x;
    if (t < 8) S[t] = 0.0;
    if (t < FF) {
        float a1 = 0.f, a2 = 0.f;
        for (int g = 0; g < RG; ++g) {
            float w = Wresh[t * RG + g];
            a1 = fmaf(w, W1[g], a1);
            a2 = fmaf(w, W2[g], a2);
        }
        head[t]     = a1;
        head[8 + t] = a2;
    } else if (t == FF) {
        float a1 = 0.f, a2 = 0.f;
        for (int g = 0; g < RG; ++g) {
            a1 = fmaf(bresh[g], W1[g], a1);
            a2 = fmaf(bresh[g], W2[g], a2);
        }
        head[6]  = a1 + b1[0];
        head[14] = a2 + b2[0];
    }
}

__global__ __launch_bounds__(256)
void finish_norm(const double* __restrict__ part, int cnt, double* __restrict__ S) {
    __shared__ double sh[8];
    int wid = threadIdx.x >> 6, lane = threadIdx.x & 63;
    double s1 = 0.0, s2 = 0.0;
    for (int i = threadIdx.x; i < cnt; i += 256) {
        s1 += part[2 * i];
        s2 += part[2 * i + 1];
    }
    #pragma unroll
    for (int o = 32; o > 0; o >>= 1) {
        s1 += __shfl_down(s1, o, 64);
        s2 += __shfl_down(s2, o, 64);
    }
    if (lane == 0) { sh[wid * 2] = s1; sh[wid * 2 + 1] = s2; }
    __syncthreads();
    if (threadIdx.x == 0) {
        S[0] = sh[0] + sh[2] + sh[4] + sh[6];
        S[1] = sh[1] + sh[3] + sh[5] + sh[7];
    }
}

// ---------- pass A: bin by src-window ----------

__global__ __launch_bounds__(256)
void hist_src(const int* __restrict__ ei, unsigned* __restrict__ cntA) {
    __shared__ unsigned hist[NSB];
    for (int b = threadIdx.x; b < NSB; b += 256) hist[b] = 0u;
    __syncthreads();
    int e0 = blockIdx.x * CHUNK;
    for (int i = threadIdx.x; i < CHUNK; i += 256) {
        int e = e0 + i;
        if (e < EE) {
            int s = __builtin_nontemporal_load(ei + e) % NN;
            atomicAdd(&hist[s >> SBSH], 1u);
        }
    }
    __syncthreads();
    for (int b = threadIdx.x; b < NSB; b += 256)
        cntA[(size_t)blockIdx.x * NSB + b] = hist[b];
}

template <int NBINS>
__global__ __launch_bounds__(1024)
void scan_bins(unsigned* __restrict__ cnt, unsigned* __restrict__ tot) {
    __shared__ unsigned ls[1024];
    int b = blockIdx.x, t = threadIdx.x;
    unsigned v = (t < NBLK) ? cnt[(size_t)t * NBINS + b] : 0u;
    ls[t] = v;
    __syncthreads();
    for (int o = 1; o < 1024; o <<= 1) {
        unsigned add = (t >= o) ? ls[t - o] : 0u;
        __syncthreads();
        ls[t] += add;
        __syncthreads();
    }
    if (t < NBLK) cnt[(size_t)t * NBINS + b] = ls[t] - v;
    if (t == 1023) tot[b] = ls[1023];
}

__global__ __launch_bounds__(1024)
void scan_totals(const unsigned* __restrict__ tot, int* __restrict__ start, int n) {
    __shared__ unsigned ls[1024];
    int t = threadIdx.x;
    unsigned v = (t < n) ? tot[t] : 0u;
    ls[t] = v;
    __syncthreads();
    for (int o = 1; o < 1024; o <<= 1) {
        unsigned add = (t >= o) ? ls[t - o] : 0u;
        __syncthreads();
        ls[t] += add;
        __syncthreads();
    }
    if (t < n) start[t] = (int)(ls[t] - v);
    if (t == 1023) start[n] = (int)ls[1023];
}

// pass A scatter: SoA kv = {src | dl<<17, ea 2xbf16} (8B), bk = dst bucket (1B)
__global__ __launch_bounds__(512)
void scatter_src(const int* __restrict__ ei, const float* __restrict__ eattr,
                 const unsigned* __restrict__ cntA, const int* __restrict__ segStart,
                 uv2* __restrict__ kv, unsigned char* __restrict__ bk) {
    __shared__ unsigned cur[NSB];
    __shared__ unsigned hist[NSB];
    __shared__ unsigned scn[256];
    __shared__ uv2 stage[SUB];
    __shared__ unsigned char stageB[SUB];
    int blk = blockIdx.x;
    int tid = threadIdx.x;
    for (int b = tid; b < NSB; b += 512)
        cur[b] = (unsigned)segStart[b] + cntA[(size_t)blk * NSB + b];
    int e0 = blk * CHUNK;
    for (int s = 0; s < NSUBB; ++s) {
        for (int b = tid; b < NSB; b += 512) hist[b] = 0u;
        __syncthreads();
        int sb0 = e0 + s * SUB;
        unsigned rk[8]; uv2 rc[8]; int bn[8]; unsigned char bb[8]; bool val[8];
        #pragma unroll
        for (int j = 0; j < 8; ++j) {
            int e = sb0 + j * 512 + tid;
            val[j] = e < EE;
            int ss = 0, dd = 0;
            fv2 ea; ea.x = 0.f; ea.y = 0.f;
            if (val[j]) {
                ss = __builtin_nontemporal_load(ei + e) % NN;
                dd = __builtin_nontemporal_load(ei + EE + e) % NN;
                ea = __builtin_nontemporal_load(reinterpret_cast<const fv2*>(eattr) + e);
            }
            bn[j] = ss >> SBSH;
            rc[j].x = (unsigned)ss | ((unsigned)(dd & (DBN - 1)) << 17);
            rc[j].y = f2bf(ea.x) | (f2bf(ea.y) << 16);
            bb[j] = (unsigned char)(dd >> DBSH);
            if (val[j]) rk[j] = atomicAdd(&hist[bn[j]], 1u);
        }
        __syncthreads();
        if (tid < 256) scn[tid] = (tid < NSB) ? hist[tid] : 0u;
        __syncthreads();
        for (int o = 1; o < 256; o <<= 1) {
            unsigned add = 0u;
            if (tid < 256 && tid >= o) add = scn[tid - o];
            __syncthreads();
            if (tid < 256) scn[tid] += add;
            __syncthreads();
        }
        #pragma unroll
        for (int j = 0; j < 8; ++j) {
            if (val[j]) {
                unsigned ex = bn[j] ? scn[bn[j] - 1] : 0u;
                stage[ex + rk[j]]  = rc[j];
                stageB[ex + rk[j]] = bb[j];
            }
        }
        __syncthreads();
        int subCnt = (int)scn[NSB - 1];
        for (int i = tid; i < subCnt; i += 512) {
            uv2 r = stage[i];
            unsigned b = (r.x & 0x1FFFFu) >> SBSH;
            unsigned ex = b ? scn[b - 1] : 0u;
            unsigned pos = cur[b] + (unsigned)i - ex;
            kv[pos] = r;
            bk[pos] = stageB[i];
        }
        __syncthreads();
        for (int b = tid; b < NSB; b += 512) cur[b] += hist[b];
        __syncthreads();
    }
}

// ---------- pass B histogram (dst buckets; graph-only) ----------

__global__ __launch_bounds__(256)
void hist_dst(const unsigned char* __restrict__ bk, unsigned* __restrict__ cntB) {
    __shared__ unsigned hist[NBDST];
    for (int b = threadIdx.x; b < NBDST; b += 256) hist[b] = 0u;
    __syncthreads();
    int e0 = blockIdx.x * CHUNK;
    for (int i = threadIdx.x; i < CHUNK; i += 256) {
        int e = e0 + i;
        if (e < EE) atomicAdd(&hist[bk[e]], 1u);
    }
    __syncthreads();
    for (int b = threadIdx.x; b < NBDST; b += 256)
        cntB[(size_t)blockIdx.x * NBDST + b] = hist[b];
}

// ---------- per-layer attach + bucket scatter (SUBA=2048: longer runs, half barriers) ----------
__global__ __launch_bounds__(512)
void scatter_dst_att(const uv2* __restrict__ kv, const unsigned char* __restrict__ bk,
                     const unsigned* __restrict__ cntB, const int* __restrict__ bstart,
                     const int* __restrict__ segStart, const uv4* __restrict__ xlb,
                     uv4* __restrict__ recsA, unsigned short* __restrict__ recsD) {
    __shared__ unsigned cur[NBDST];
    __shared__ unsigned hist[NBDST];
    __shared__ unsigned scn[256];
    __shared__ uv4 win[2][DBN];            // 16 KB
    __shared__ uv4 stA[SUBA];              // 32 KB
    __shared__ unsigned short stD[SUBA];   // 4 KB
    __shared__ unsigned char sbin[SUBA];   // 2 KB
    __shared__ int w0s;
    int blk = blockIdx.x;
    int tid = threadIdx.x;
    int e0 = blk * CHUNK;
    if (tid == 0) w0s = 0;
    __syncthreads();
    if (tid < NSB && segStart[tid] <= e0 && e0 < segStart[tid + 1]) w0s = tid;
    __syncthreads();
    int w0 = w0s;
    int w1 = min(w0 + 1, NSB - 1);
    for (int i = tid; i < DBN; i += 512) {
        int g0 = (w0 << SBSH) + i;
        int g1 = (w1 << SBSH) + i;
        uv4 z; z.x = 0u; z.y = 0u; z.z = 0u; z.w = 0u;
        win[0][i] = (g0 < NN) ? xlb[g0] : z;
        win[1][i] = (g1 < NN) ? xlb[g1] : z;
    }
    for (int b = tid; b < NBDST; b += 512)
        cur[b] = (unsigned)bstart[b] + cntB[(size_t)blk * NBDST + b];
    __syncthreads();

    for (int s = 0; s < NSUBA; ++s) {
        for (int b = tid; b < NBDST; b += 512) hist[b] = 0u;
        __syncthreads();
        int sb0 = e0 + s * SUBA;
        unsigned rk[4]; uv4 rc[4]; unsigned short dl2[4]; int bn[4]; bool val[4];
        #pragma unroll
        for (int j = 0; j < 4; ++j) {
            int e = sb0 + j * 512 + tid;
            val[j] = e < EE;
            uv2 r; r.x = 0u; r.y = 0u;
            int b = 0;
            if (val[j]) {
                r = __builtin_nontemporal_load(kv + e);
                b = (int)bk[e];
            }
            int src = (int)(r.x & 0x1FFFFu);
            int sel = min(max((src >> SBSH) - w0, 0), 1);
            uv4 q = win[sel][src & (DBN - 1)];
            rc[j].x = r.y;
            rc[j].y = q.x;
            rc[j].z = q.y;
            rc[j].w = q.z;
            dl2[j] = (unsigned short)((r.x >> 17) & (DBN - 1));
            bn[j] = b;
            if (val[j]) rk[j] = atomicAdd(&hist[bn[j]], 1u);
        }
        __syncthreads();
        if (tid < 256) scn[tid] = (tid < NBDST) ? hist[tid] : 0u;
        __syncthreads();
        for (int o = 1; o < 256; o <<= 1) {
            unsigned add = 0u;
            if (tid < 256 && tid >= o) add = scn[tid - o];
            __syncthreads();
            if (tid < 256) scn[tid] += add;
            __syncthreads();
        }
        #pragma unroll
        for (int j = 0; j < 4; ++j) {
            if (val[j]) {
                unsigned ex = bn[j] ? scn[bn[j] - 1] : 0u;
                unsigned p = ex + rk[j];
                stA[p] = rc[j];
                stD[p] = dl2[j];
                sbin[p] = (unsigned char)bn[j];
            }
        }
        __syncthreads();
        int subCnt = (int)scn[NBDST - 1];
        for (int i = tid; i < subCnt; i += 512) {
            unsigned b = sbin[i];
            unsigned ex = b ? scn[b - 1] : 0u;
            unsigned pos = cur[b] + (unsigned)i - ex;
            recsA[pos] = stA[i];
            recsD[pos] = stD[i];
        }
        __syncthreads();
        for (int b = tid; b < NBDST; b += 512) cur[b] += hist[b];
        __syncthreads();
    }
}

// ---------- fused LDS sort + register reduce (R16, proven) ----------
__global__ __launch_bounds__(512)
void sort_reduce(const uv4* __restrict__ recsA, const unsigned short* __restrict__ recsD,
                 const int* __restrict__ bstart, const uv4* __restrict__ xrb,
                 const float* __restrict__ Wef, const float* __restrict__ attf,
                 float* __restrict__ partG) {
    __shared__ uv4 stage[SPASS];      // 32 KB
    __shared__ unsigned hist[DBN];    // 2 KB
    __shared__ unsigned scn[DBN];     // 2 KB
    int b = blockIdx.x / PSEG, s = blockIdx.x % PSEG;
    int b0 = bstart[b], b1 = bstart[b + 1], len = b1 - b0;
    int k0 = b0 + (int)(((long long)len * s) / PSEG);
    int k1 = b0 + (int)(((long long)len * (s + 1)) / PSEG);
    int tid = threadIdx.x;

    float we0[FF], we1[FF], at[FF];
    #pragma unroll
    for (int f = 0; f < FF; ++f) { we0[f] = Wef[f]; we1[f] = Wef[FF + f]; at[f] = attf[f]; }
    int n = (b << DBSH) + tid;
    float bv[FF] = {0.f, 0.f, 0.f, 0.f, 0.f, 0.f};
    if (n < NN) {
        uv4 r = xrb[n];
        bv[0] = __uint_as_float(r.x << 16);  bv[1] = __uint_as_float(r.x & 0xFFFF0000u);
        bv[2] = __uint_as_float(r.y << 16);  bv[3] = __uint_as_float(r.y & 0xFFFF0000u);
        bv[4] = __uint_as_float(r.z << 16);  bv[5] = __uint_as_float(r.z & 0xFFFF0000u);
    }
    float acc[7] = {0.f, 0.f, 0.f, 0.f, 0.f, 0.f, 0.f};

    for (int base = k0; base < k1; base += SPASS) {
        hist[tid] = 0u;
        __syncthreads();
        unsigned rk[4]; uv4 rc[4]; int dl[4]; bool val[4];
        #pragma unroll
        for (int j = 0; j < 4; ++j) {
            int k = base + j * 512 + tid;
            val[j] = k < k1;
            uv4 r; r.x = 0u; r.y = 0u; r.z = 0u; r.w = 0u;
            int d = 0;
            if (val[j]) {
                r = __builtin_nontemporal_load(recsA + k);
                d = (int)recsD[k];
            }
            rc[j] = r;
            dl[j] = d;
            if (val[j]) rk[j] = atomicAdd(&hist[d], 1u);
        }
        __syncthreads();
        scn[tid] = hist[tid];
        __syncthreads();
        for (int o = 1; o < DBN; o <<= 1) {
            unsigned add = (tid >= o) ? scn[tid - o] : 0u;
            __syncthreads();
            scn[tid] += add;
            __syncthreads();
        }
        #pragma unroll
        for (int j = 0; j < 4; ++j) {
            if (val[j]) {
                unsigned ex = dl[j] ? scn[dl[j] - 1] : 0u;
                stage[ex + rk[j]] = rc[j];
            }
        }
        __syncthreads();
        unsigned e0s = scn[tid] - hist[tid], e1s = scn[tid];
        for (unsigned j = e0s; j < e1s; ++j) {
            uv4 a = stage[j];
            float eax = __uint_as_float(a.x << 16);
            float eay = __uint_as_float(a.x & 0xFFFF0000u);
            float av[FF];
            av[0] = __uint_as_float(a.y << 16);  av[1] = __uint_as_float(a.y & 0xFFFF0000u);
            av[2] = __uint_as_float(a.z << 16);  av[3] = __uint_as_float(a.z & 0xFFFF0000u);
            av[4] = __uint_as_float(a.w << 16);  av[5] = __uint_as_float(a.w & 0xFFFF0000u);
            float logit = 0.f;
            #pragma unroll
            for (int f = 0; f < FF; ++f) {
                float m = av[f] + bv[f] + fmaf(eay, we1[f], eax * we0[f]);
                m = m >= 0.f ? m : 0.2f * m;
                logit = fmaf(at[f], m, logit);
            }
            float w = __expf(logit);
            acc[6] += w;
            #pragma unroll
            for (int f = 0; f < FF; ++f) acc[f] = fmaf(w, av[f], acc[f]);
        }
        __syncthreads();
    }
    float* dst = partG + (size_t)blockIdx.x * ACCW;
    #pragma unroll
    for (int f = 0; f < 7; ++f) dst[f * DBN + tid] = acc[f];
}

// ---------- merge partials + finalize (one block of 512 per bucket) ----------
template <int LAYER, int QSL>
__global__ __launch_bounds__(512)
void merge_finalize(const float* __restrict__ partG, const float* __restrict__ biasg,
                    const float* __restrict__ x0, const float* __restrict__ x1n0,
                    const float* __restrict__ x2,
                    float* __restrict__ h, double* __restrict__ part) {
    __shared__ double shd[16];
    int b = blockIdx.x;
    int nb0 = b << DBSH;
    int nl = threadIdx.x;
    int cnt = min(DBN, NN - nb0);
    double s1 = 0.0, s2 = 0.0;
    if (nl < cnt) {
        size_t n = nb0 + nl;
        const float* pa = partG + (size_t)b * QSL * ACCW;
        float a[7];
        #pragma unroll
        for (int f = 0; f < 7; ++f) {
            float v = 0.f;
            #pragma unroll
            for (int q = 0; q < QSL; ++q) v += pa[q * ACCW + f * DBN + nl];
            a[f] = v;
        }
        float inv = a[6] != 0.f ? 1.f / a[6] : 0.f;
        #pragma unroll
        for (int f = 0; f < FF; ++f) {
            float t = leakyf(a[f] * inv + biasg[f], 0.01f);
            t += x0[n * FF + f];
            if (LAYER == 1) t += x1n0[n * FF + f] + x2[n * FF + f];
            h[n * FF + f] = t;
            s1 += t;
            s2 += (double)t * (double)t;
        }
    }
    int wid = threadIdx.x >> 6, lane = threadIdx.x & 63;
    #pragma unroll
    for (int o = 32; o > 0; o >>= 1) {
        s1 += __shfl_down(s1, o, 64);
        s2 += __shfl_down(s2, o, 64);
    }
    if (lane == 0) { shd[wid * 2] = s1; shd[wid * 2 + 1] = s2; }
    __syncthreads();
    if (threadIdx.x == 0) {
        double t1 = 0.0, t2 = 0.0;
        #pragma unroll
        for (int w = 0; w < 8; ++w) { t1 += shd[w * 2]; t2 += shd[w * 2 + 1]; }
        part[b * 2 + 0] = t1;
        part[b * 2 + 1] = t2;
    }
}

// ---------- node transform: xlb + xrb, both bf16 packed (16B/node) ----------
template <int LAYER>
__global__ __launch_bounds__(NODE_BLOCK)
void node_transform(const float* __restrict__ xin, const double* __restrict__ Snorm,
                    const float* __restrict__ Wl, const float* __restrict__ bl,
                    const float* __restrict__ Wr, const float* __restrict__ br,
                    uv4* __restrict__ xlb, uv4* __restrict__ xrb,
                    float* __restrict__ x2out) {
    int n = blockIdx.x * blockDim.x + threadIdx.x;
    if (n >= NN) return;
    float v[FF];
    if (LAYER == 0) {
        #pragma unroll
        for (int f = 0; f < FF; ++f) v[f] = xin[n * FF + f];
    } else {
        float mu, istd;
        norm_params(Snorm, mu, istd);
        #pragma unroll
        for (int f = 0; f < FF; ++f) {
            v[f] = (xin[n * FF + f] - mu) * istd;
            x2out[n * FF + f] = v[f];
        }
    }
    float ol[FF], orr[FF];
    #pragma unroll
    for (int j = 0; j < FF; ++j) { ol[j] = bl[j]; orr[j] = br[j]; }
    #pragma unroll
    for (int k = 0; k < FF; ++k) {
        float vk = v[k];
        #pragma unroll
        for (int j = 0; j < FF; ++j) {
            ol[j]  = fmaf(vk, Wl[k * FF + j], ol[j]);
            orr[j] = fmaf(vk, Wr[k * FF + j], orr[j]);
        }
    }
    uv4 q;
    q.x = f2bf(ol[0]) | (f2bf(ol[1]) << 16);
    q.y = f2bf(ol[2]) | (f2bf(ol[3]) << 16);
    q.z = f2bf(ol[4]) | (f2bf(ol[5]) << 16);
    q.w = 0u;
    xlb[n] = q;
    uv4 r;
    r.x = f2bf(orr[0]) | (f2bf(orr[1]) << 16);
    r.y = f2bf(orr[2]) | (f2bf(orr[3]) << 16);
    r.z = f2bf(orr[4]) | (f2bf(orr[5]) << 16);
    r.w = 0u;
    xrb[n] = r;
}

// ---------- FALLBACK kernels (R12, proven) ----------
__global__ __launch_bounds__(512)
void scatter_dst(const uv2* __restrict__ kv, const unsigned char* __restrict__ bk,
                 const unsigned* __restrict__ cntB, const int* __restrict__ bstart,
                 uv2* __restrict__ recs) {
    __shared__ unsigned cur[NBDST];
    __shared__ unsigned hist[NBDST];
    __shared__ unsigned scn[256];
    __shared__ uv2 stage[SUB];
    __shared__ unsigned char sbin[SUB];
    int blk = blockIdx.x;
    int tid = threadIdx.x;
    for (int b = tid; b < NBDST; b += 512)
        cur[b] = (unsigned)bstart[b] + cntB[(size_t)blk * NBDST + b];
    int e0 = blk * CHUNK;
    for (int s = 0; s < NSUBB; ++s) {
        for (int b = tid; b < NBDST; b += 512) hist[b] = 0u;
        __syncthreads();
        int sb0 = e0 + s * SUB;
        unsigned rk[8]; uv2 rc[8]; int bn[8]; bool val[8];
        #pragma unroll
        for (int j = 0; j < 8; ++j) {
            int e = sb0 + j * 512 + tid;
            val[j] = e < EE;
            uv2 r; r.x = 0u; r.y = 0u;
            int b = 0;
            if (val[j]) {
                r = __builtin_nontemporal_load(kv + e);
                b = (int)bk[e];
            }
            rc[j] = r;
            bn[j] = b;
            if (val[j]) rk[j] = atomicAdd(&hist[bn[j]], 1u);
        }
        __syncthreads();
        if (tid < 256) scn[tid] = (tid < NBDST) ? hist[tid] : 0u;
        __syncthreads();
        for (int o = 1; o < 256; o <<= 1) {
            unsigned add = 0u;
            if (tid < 256 && tid >= o) add = scn[tid - o];
            __syncthreads();
            if (tid < 256) scn[tid] += add;
            __syncthreads();
        }
        #pragma unroll
        for (int j = 0; j < 8; ++j) {
            if (val[j]) {
                unsigned ex = bn[j] ? scn[bn[j] - 1] : 0u;
                stage[ex + rk[j]] = rc[j];
                sbin[ex + rk[j]] = (unsigned char)bn[j];
            }
        }
        __syncthreads();
        int subCnt = (int)scn[NBDST - 1];
        for (int i = tid; i < subCnt; i += 512) {
            uv2 r = stage[i];
            unsigned b = sbin[i];
            unsigned ex = b ? scn[b - 1] : 0u;
            recs[cur[b] + (unsigned)i - ex] = r;
        }
        __syncthreads();
        for (int b = tid; b < NBDST; b += 512) cur[b] += hist[b];
        __syncthreads();
    }
}

__device__ __forceinline__ void edge_math(unsigned eaw, unsigned a01, unsigned a23, unsigned a45,
                                          int dl, bool valid,
                                          float (&acc)[7][DBN], const uv4* __restrict__ xrl,
                                          const float we0[FF], const float we1[FF],
                                          const float at[FF]) {
    uv4 r = xrl[dl];
    float eax = __uint_as_float(eaw << 16);
    float eay = __uint_as_float(eaw & 0xFFFF0000u);
    float av[FF], bv[FF];
    av[0] = __uint_as_float(a01 << 16);  av[1] = __uint_as_float(a01 & 0xFFFF0000u);
    av[2] = __uint_as_float(a23 << 16);  av[3] = __uint_as_float(a23 & 0xFFFF0000u);
    av[4] = __uint_as_float(a45 << 16);  av[5] = __uint_as_float(a45 & 0xFFFF0000u);
    bv[0] = __uint_as_float(r.x << 16);  bv[1] = __uint_as_float(r.x & 0xFFFF0000u);
    bv[2] = __uint_as_float(r.y << 16);  bv[3] = __uint_as_float(r.y & 0xFFFF0000u);
    bv[4] = __uint_as_float(r.z << 16);  bv[5] = __uint_as_float(r.z & 0xFFFF0000u);
    float logit = 0.f;
    #pragma unroll
    for (int f = 0; f < FF; ++f) {
        float m = av[f] + bv[f] + fmaf(eay, we1[f], eax * we0[f]);
        m = m >= 0.f ? m : 0.2f * m;
        logit = fmaf(at[f], m, logit);
    }
    float w = __expf(logit);
    w = valid ? w : 0.f;
    atomicAdd(&acc[6][dl], w);
    #pragma unroll
    for (int f = 0; f < FF; ++f) atomicAdd(&acc[f][dl], w * av[f]);
}

template <int QSL>
__global__ __launch_bounds__(256)
void gat_gather_div(const int* __restrict__ bucketStart, const uv2* __restrict__ recs,
                    const uv4* __restrict__ xlb, const uv4* __restrict__ xrb,
                    const float* __restrict__ Wef, const float* __restrict__ attf,
                    float* __restrict__ partG) {
    __shared__ float acc[7][DBN];
    __shared__ uv4 xrl[DBN];
    int b  = blockIdx.x / QSL;
    int qq = blockIdx.x % QSL;
    int nb0 = b << DBSH;
    int cnt = min(DBN, NN - nb0);

    for (int i = threadIdx.x; i < 7 * DBN; i += 256) acc[0][i] = 0.f;
    for (int i = threadIdx.x; i < cnt; i += 256) xrl[i] = xrb[nb0 + i];
    float we0[FF], we1[FF], at[FF];
    #pragma unroll
    for (int f = 0; f < FF; ++f) { we0[f] = Wef[f]; we1[f] = Wef[FF + f]; at[f] = attf[f]; }
    __syncthreads();

    int bk0 = bucketStart[b], bk1 = bucketStart[b + 1];
    int len = bk1 - bk0;
    int k0 = bk0 + (int)(((long long)len * qq) / QSL);
    int k1 = bk0 + (int)(((long long)len * (qq + 1)) / QSL);
    int last = k1 - 1;
    for (int base = k0 + threadIdx.x * 4; base < k1; base += 1024) {
        uv2 rA = __builtin_nontemporal_load(recs + base);
        uv2 rB = __builtin_nontemporal_load(recs + min(base + 1, last));
        uv2 rC = __builtin_nontemporal_load(recs + min(base + 2, last));
        uv2 rD = __builtin_nontemporal_load(recs + min(base + 3, last));
        uv4 qA = xlb[rA.x & 0x1FFFF];
        uv4 qB = xlb[rB.x & 0x1FFFF];
        uv4 qC = xlb[rC.x & 0x1FFFF];
        uv4 qD = xlb[rD.x & 0x1FFFF];
        bool vB = base + 1 < k1, vC = base + 2 < k1, vD = base + 3 < k1;
        edge_math(rA.y, qA.x, qA.y, qA.z, (rA.x >> 17) & (DBN - 1), true, acc, xrl, we0, we1, at);
        edge_math(rB.y, qB.x, qB.y, qB.z, (rB.x >> 17) & (DBN - 1), vB,   acc, xrl, we0, we1, at);
        edge_math(rC.y, qC.x, qC.y, qC.z, (rC.x >> 17) & (DBN - 1), vC,   acc, xrl, we0, we1, at);
        edge_math(rD.y, qD.x, qD.y, qD.z, (rD.x >> 17) & (DBN - 1), vD,   acc, xrl, we0, we1, at);
    }
    __syncthreads();

    float* dst = partG + (size_t)blockIdx.x * ACCW;
    for (int i = threadIdx.x; i < ACCW; i += 256) dst[i] = acc[0][i];
}

// ---------- FFN ----------
template <int LAYER>
__global__ __launch_bounds__(NODE_BLOCK)
void node_ffn(const float* __restrict__ h, const double* __restrict__ Snorm,
              const float* __restrict__ f1W, const float* __restrict__ f1b,
              const float* __restrict__ f2W, const float* __restrict__ f2b,
              const float* __restrict__ x0, const float* __restrict__ x1n0_in,
              const float* __restrict__ x2,
              float* __restrict__ x1n0_out, float* __restrict__ gout,
              double* __restrict__ part,
              const float* __restrict__ head, float* __restrict__ dout) {
    __shared__ double sh[8];
    int n = blockIdx.x * blockDim.x + threadIdx.x;
    double s1 = 0.0, s2 = 0.0;
    if (n < NN) {
        float mu, istd;
        norm_params(Snorm, mu, istd);
        float xn[FF];
        #pragma unroll
        for (int f = 0; f < FF; ++f) xn[f] = (h[n * FF + f] - mu) * istd;

        float u[FF], w[FF];
        #pragma unroll
        for (int j = 0; j < FF; ++j) u[j] = f1b[j];
        #pragma unroll
        for (int k = 0; k < FF; ++k) {
            float vk = xn[k];
            #pragma unroll
            for (int j = 0; j < FF; ++j) u[j] = fmaf(vk, f1W[k * FF + j], u[j]);
        }
        #pragma unroll
        for (int j = 0; j < FF; ++j) u[j] = leakyf(u[j], 0.01f);
        #pragma unroll
        for (int j = 0; j < FF; ++j) w[j] = f2b[j];
        #pragma unroll
        for (int k = 0; k < FF; ++k) {
            float vk = u[k];
            #pragma unroll
            for (int j = 0; j < FF; ++j) w[j] = fmaf(vk, f2W[k * FF + j], w[j]);
        }
        #pragma unroll
        for (int f = 0; f < FF; ++f) {
            w[f] += xn[f] + x0[n * FF + f];
            if (LAYER == 1) w[f] += x2[n * FF + f] + x1n0_in[n * FF + f];
        }
        if (LAYER == 0) {
            #pragma unroll
            for (int f = 0; f < FF; ++f) {
                x1n0_out[n * FF + f] = xn[f];
                gout[n * FF + f]     = w[f];
                s1 += w[f];
                s2 += (double)w[f] * (double)w[f];
            }
        } else {
            float o1 = head[6], o2 = head[14];
            #pragma unroll
            for (int f = 0; f < FF; ++f) {
                o1 = fmaf(w[f], head[f], o1);
                o2 = fmaf(w[f], head[8 + f], o2);
            }
            dout[n * 2 + 0] = o1;
            dout[n * 2 + 1] = o2;
        }
    }
    if (LAYER == 0) {
        int wid = threadIdx.x >> 6, lane = threadIdx.x & 63;
        #pragma unroll
        for (int o = 32; o > 0; o >>= 1) {
            s1 += __shfl_down(s1, o, 64);
            s2 += __shfl_down(s2, o, 64);
        }
        if (lane == 0) { sh[wid * 2] = s1; sh[wid * 2 + 1] = s2; }
        __syncthreads();
        if (threadIdx.x == 0) {
            part[blockIdx.x * 2 + 0] = sh[0] + sh[2] + sh[4] + sh[6];
            part[blockIdx.x * 2 + 1] = sh[1] + sh[3] + sh[5] + sh[7];
        }
    }
}

// ---------------------------------------------------------------

extern "C" void kernel_launch(void* const* d_in, const int* in_sizes, int n_in,
                              void* d_out, int out_size, void* d_ws, size_t ws_size,
                              hipStream_t stream) {
    const float* x     = (const float*)d_in[0];
    const float* eattr = (const float*)d_in[1];
    const float* Wl    = (const float*)d_in[2];
    const float* bl    = (const float*)d_in[3];
    const float* Wr    = (const float*)d_in[4];
    const float* br    = (const float*)d_in[5];
    const float* We    = (const float*)d_in[6];
    const float* att   = (const float*)d_in[7];
    const float* biasg = (const float*)d_in[8];
    const float* ff1W  = (const float*)d_in[9];
    const float* ff1b  = (const float*)d_in[10];
    const float* ff2W  = (const float*)d_in[11];
    const float* ff2b  = (const float*)d_in[12];
    const float* Wresh = (const float*)d_in[13];
    const float* bresh = (const float*)d_in[14];
    const float* W1    = (const float*)d_in[15];
    const float* b1    = (const float*)d_in[16];
    const float* W2    = (const float*)d_in[17];
    const float* b2    = (const float*)d_in[18];
    const int*   ei    = (const int*)d_in[19];
    float* out = (float*)d_out;

    char* p = (char*)d_ws;
    auto alloc = [&](size_t bytes) -> char* {
        char* r = p;
        p += (bytes + 255) & ~size_t(255);
        return r;
    };

    // ---- common prefix ----
    double*   S        = (double*)alloc(8 * sizeof(double));
    float*    head     = (float*)alloc(16 * sizeof(float));
    double*   partMA   = (double*)alloc((size_t)NBDST * 2 * sizeof(double));
    double*   partMB   = (double*)alloc((size_t)NBDST * 2 * sizeof(double));
    double*   partF    = (double*)alloc((size_t)NODE_GRID * 2 * sizeof(double));
    uv4*      xlb      = (uv4*)alloc((size_t)NN * sizeof(uv4));
    uv4*      xrb      = (uv4*)alloc((size_t)NN * sizeof(uv4));
    float*    h        = (float*)alloc((size_t)NN * FF * sizeof(float));
    float*    x1n0     = (float*)alloc((size_t)NN * FF * sizeof(float));
    float*    x2       = (float*)alloc((size_t)NN * FF * sizeof(float));
    float*    g        = (float*)alloc((size_t)NN * FF * sizeof(float));
    unsigned* cntA     = (unsigned*)alloc((size_t)NBLK * NSB * sizeof(unsigned));
    unsigned* totA     = (unsigned*)alloc((size_t)NSB * sizeof(unsigned));
    int*      segStart = (int*)alloc((size_t)(NSB + 1) * sizeof(int));
    unsigned* cntB     = (unsigned*)alloc((size_t)NBLK * NBDST * sizeof(unsigned));
    unsigned* totB     = (unsigned*)alloc((size_t)NBDST * sizeof(unsigned));
    int*      bstart   = (int*)alloc((size_t)(NBDST + 1) * sizeof(int));
    uv2*      kv       = (uv2*)alloc((size_t)EE * sizeof(uv2));              // 51.2 MB
    unsigned char* bk  = (unsigned char*)alloc((size_t)EE);                  // 6.4 MB
    char* tail = p;
    // ---- fast-path tail ----
    unsigned short* recsDs = (unsigned short*)alloc((size_t)EE * 2);         // 12.8 MB
    uv4*      recsAs   = (uv4*)alloc((size_t)EE * sizeof(uv4));              // 102.4 MB
    float*    partG    = (float*)alloc((size_t)NBDST * PSEG * ACCW * sizeof(float)); // 11.2 MB
    size_t need_fast = (size_t)(p - (char*)d_ws);
    bool fast = need_fast <= ws_size;
    // ---- fallback tail (overlaps fast tail; kv overlaid for partG) ----
    uv2*   recsFb  = (uv2*)tail;
    float* partGfb = (float*)kv;

    head_prep<<<1, 64, 0, stream>>>(Wresh, bresh, W1, b1, W2, b2, head, S);

    // ---- graph-only build ----
    hist_src<<<NBLK, 256, 0, stream>>>(ei, cntA);
    scan_bins<NSB><<<NSB, 1024, 0, stream>>>(cntA, totA);
    scan_totals<<<1, 1024, 0, stream>>>(totA, segStart, NSB);
    scatter_src<<<NBLK, 512, 0, stream>>>(ei, eattr, cntA, segStart, kv, bk);
    hist_dst<<<NBLK, 256, 0, stream>>>(bk, cntB);
    scan_bins<NBDST><<<NBDST, 1024, 0, stream>>>(cntB, totB);
    scan_totals<<<1, 1024, 0, stream>>>(totB, bstart, NBDST);

    if (fast) {
        // ---- layer 0 ----
        node_transform<0><<<NODE_GRID, NODE_BLOCK, 0, stream>>>(
            x, nullptr, Wl, bl, Wr, br, xlb, xrb, nullptr);
        scatter_dst_att<<<NBLK, 512, 0, stream>>>(
            kv, bk, cntB, bstart, segStart, xlb, recsAs, recsDs);
        sort_reduce<<<NBDST * PSEG, 512, 0, stream>>>(
            recsAs, recsDs, bstart, xrb, We, att, partG);
        merge_finalize<0, PSEG><<<NBDST, 512, 0, stream>>>(
            partG, biasg, x, nullptr, nullptr, h, partMA);
        finish_norm<<<1, 256, 0, stream>>>(partMA, NBDST, S + 0);
        node_ffn<0><<<NODE_GRID, NODE_BLOCK, 0, stream>>>(
            h, S + 0, ff1W, ff1b, ff2W, ff2b, x, nullptr, nullptr,
            x1n0, g, partF, nullptr, nullptr);
        finish_norm<<<1, 256, 0, stream>>>(partF, NODE_GRID, S + 2);

        // ---- layer 1 ----
        node_transform<1><<<NODE_GRID, NODE_BLOCK, 0, stream>>>(
            g, S + 2, Wl + 36, bl + 6, Wr + 36, br + 6, xlb, xrb, x2);
        scatter_dst_att<<<NBLK, 512, 0, stream>>>(
            kv, bk, cntB, bstart, segStart, xlb, recsAs, recsDs);
        sort_reduce<<<NBDST * PSEG, 512, 0, stream>>>(
            recsAs, recsDs, bstart, xrb, We + 12, att + 6, partG);
        merge_finalize<1, PSEG><<<NBDST, 512, 0, stream>>>(
            partG, biasg + 6, x, x1n0, x2, h, partMB);
        finish_norm<<<1, 256, 0, stream>>>(partMB, NBDST, S + 4);
        node_ffn<1><<<NODE_GRID, NODE_BLOCK, 0, stream>>>(
            h, S + 4, ff1W + 36, ff1b + 6, ff2W + 36, ff2b + 6, x, x1n0, x2,
            nullptr, nullptr, nullptr, head, out);
    } else {
        // ---- fallback: R12 structure ----
        scatter_dst<<<NBLK, 512, 0, stream>>>(kv, bk, cntB, bstart, recsFb);

        node_transform<0><<<NODE_GRID, NODE_BLOCK, 0, stream>>>(
            x, nullptr, Wl, bl, Wr, br, xlb, xrb, nullptr);
        gat_gather_div<QSD><<<NBDST * QSD, 256, 0, stream>>>(
            bstart, recsFb, xlb, xrb, We, att, partGfb);
        merge_finalize<0, QSD><<<NBDST, 512, 0, stream>>>(
            partGfb, biasg, x, nullptr, nullptr, h, partMA);
        finish_norm<<<1, 256, 0, stream>>>(partMA, NBDST, S + 0);
        node_ffn<0><<<NODE_GRID, NODE_BLOCK, 0, stream>>>(
            h, S + 0, ff1W, ff1b, ff2W, ff2b, x, nullptr, nullptr,
            x1n0, g, partF, nullptr, nullptr);
        finish_norm<<<1, 256, 0, stream>>>(partF, NODE_GRID, S + 2);

        node_transform<1><<<NODE_GRID, NODE_BLOCK, 0, stream>>>(
            g, S + 2, Wl + 36, bl + 6, Wr + 36, br + 6, xlb, xrb, x2);
        gat_gather_div<QSD><<<NBDST * QSD, 256, 0, stream>>>(
            bstart, recsFb, xlb, xrb, We + 12, att + 6, partGfb);
        merge_finalize<1, QSD><<<NBDST, 512, 0, stream>>>(
            partGfb, biasg + 6, x, x1n0, x2, h, partMB);
        finish_norm<<<1, 256, 0, stream>>>(partMB, NBDST, S + 4);
        node_ffn<1><<<NODE_GRID, NODE_BLOCK, 0, stream>>>(
            h, S + 4, ff1W + 36, ff1b + 6, ff2W + 36, ff2b + 6, x, x1n0, x2,
            nullptr, nullptr, nullptr, head, out);
    }
}

// Round 18
// 395.091 us; speedup vs baseline: 1.7255x; 1.0161x over previous
//
#include <hip/hip_runtime.h>
#include <math.h>

// Problem constants (from reference)
constexpr int NN = 100000;          // nodes
constexpr int EE = 6400000;         // edges
constexpr int FF = 6;               // features
constexpr int RG = 500;             // reg head hidden
constexpr double MM = 600000.0;     // N*F elements for global norm

constexpr int NODE_BLOCK = 256;
constexpr int NODE_GRID  = (NN + NODE_BLOCK - 1) / NODE_BLOCK;   // 391

constexpr int CHUNK = 8192;
constexpr int NBLK  = (EE + CHUNK - 1) / CHUNK;  // 782
constexpr int SUB   = 4096;                      // pass-A LDS sort sub-batch
constexpr int NSUBB = CHUNK / SUB;               // 2
constexpr int SUBA  = 2048;                      // attach sub-batch
constexpr int NSUBA = CHUNK / SUBA;              // 4
constexpr int SBSH  = 9;                         // src window = 512 nodes
constexpr int NSB   = (NN + (1 << SBSH) - 1) >> SBSH;   // 196
constexpr int DBSH  = 9;                         // dst bucket = 512 nodes
constexpr int DBN   = 1 << DBSH;                 // 512
constexpr int NBDST = (NN + DBN - 1) >> DBSH;    // 196
constexpr int PSEG  = 4;                         // segments per bucket (sort_reduce)
constexpr int SPASS = 2048;                      // records per LDS pass
constexpr int QSD   = 10;                        // fallback gather slices
constexpr int ACCW  = 7 * DBN;                   // partial width (3584 floats)

typedef unsigned uv2 __attribute__((ext_vector_type(2)));
typedef unsigned uv4 __attribute__((ext_vector_type(4)));
typedef float    fv2 __attribute__((ext_vector_type(2)));

__device__ __forceinline__ float leakyf(float v, float s) { return v >= 0.f ? v : s * v; }

__device__ __forceinline__ unsigned f2bf(float x) {   // RNE f32 -> bf16 bits
    unsigned u = __float_as_uint(x);
    return (u + 0x7FFFu + ((u >> 16) & 1u)) >> 16;
}

__device__ __forceinline__ void norm_params(const double* __restrict__ S, float& mu, float& istd) {
    double s1 = S[0], s2 = S[1];
    double mean = s1 / MM;
    double var  = (s2 - s1 * mean) / (MM - 1.0);
    mu   = (float)mean;
    istd = (float)(1.0 / sqrt(var));
}

// K0: collapse regression head; zero norm scalars.
__global__ void head_prep(const float* __restrict__ Wresh, const float* __restrict__ bresh,
                          const float* __restrict__ W1, const float* __restrict__ b1,
                          const float* __restrict__ W2, const float* __restrict__ b2,
                          float* __restrict__ head, double* __restrict__ S) {
    int t = threadIdx.x;
    if (t < 8) S[t] = 0.0;
    if (t < FF) {
        float a1 = 0.f, a2 = 0.f;
        for (int g = 0; g < RG; ++g) {
            float w = Wresh[t * RG + g];
            a1 = fmaf(w, W1[g], a1);
            a2 = fmaf(w, W2[g], a2);
        }
        head[t]     = a1;
        head[8 + t] = a2;
    } else if (t == FF) {
        float a1 = 0.f, a2 = 0.f;
        for (int g = 0; g < RG; ++g) {
            a1 = fmaf(bresh[g], W1[g], a1);
            a2 = fmaf(bresh[g], W2[g], a2);
        }
        head[6]  = a1 + b1[0];
        head[14] = a2 + b2[0];
    }
}

__global__ __launch_bounds__(256)
void finish_norm(const double* __restrict__ part, int cnt, double* __restrict__ S) {
    __shared__ double sh[8];
    int wid = threadIdx.x >> 6, lane = threadIdx.x & 63;
    double s1 = 0.0, s2 = 0.0;
    for (int i = threadIdx.x; i < cnt; i += 256) {
        s1 += part[2 * i];
        s2 += part[2 * i + 1];
    }
    #pragma unroll
    for (int o = 32; o > 0; o >>= 1) {
        s1 += __shfl_down(s1, o, 64);
        s2 += __shfl_down(s2, o, 64);
    }
    if (lane == 0) { sh[wid * 2] = s1; sh[wid * 2 + 1] = s2; }
    __syncthreads();
    if (threadIdx.x == 0) {
        S[0] = sh[0] + sh[2] + sh[4] + sh[6];
        S[1] = sh[1] + sh[3] + sh[5] + sh[7];
    }
}

// ---------- pass A: bin by src-window ----------

__global__ __launch_bounds__(256)
void hist_src(const int* __restrict__ ei, unsigned* __restrict__ cntA) {
    __shared__ unsigned hist[NSB];
    for (int b = threadIdx.x; b < NSB; b += 256) hist[b] = 0u;
    __syncthreads();
    int e0 = blockIdx.x * CHUNK;
    for (int i = threadIdx.x; i < CHUNK; i += 256) {
        int e = e0 + i;
        if (e < EE) {
            int s = __builtin_nontemporal_load(ei + e) % NN;
            atomicAdd(&hist[s >> SBSH], 1u);
        }
    }
    __syncthreads();
    for (int b = threadIdx.x; b < NSB; b += 256)
        cntA[(size_t)blockIdx.x * NSB + b] = hist[b];
}

template <int NBINS>
__global__ __launch_bounds__(1024)
void scan_bins(unsigned* __restrict__ cnt, unsigned* __restrict__ tot) {
    __shared__ unsigned ls[1024];
    int b = blockIdx.x, t = threadIdx.x;
    unsigned v = (t < NBLK) ? cnt[(size_t)t * NBINS + b] : 0u;
    ls[t] = v;
    __syncthreads();
    for (int o = 1; o < 1024; o <<= 1) {
        unsigned add = (t >= o) ? ls[t - o] : 0u;
        __syncthreads();
        ls[t] += add;
        __syncthreads();
    }
    if (t < NBLK) cnt[(size_t)t * NBINS + b] = ls[t] - v;
    if (t == 1023) tot[b] = ls[1023];
}

__global__ __launch_bounds__(1024)
void scan_totals(const unsigned* __restrict__ tot, int* __restrict__ start, int n) {
    __shared__ unsigned ls[1024];
    int t = threadIdx.x;
    unsigned v = (t < n) ? tot[t] : 0u;
    ls[t] = v;
    __syncthreads();
    for (int o = 1; o < 1024; o <<= 1) {
        unsigned add = (t >= o) ? ls[t - o] : 0u;
        __syncthreads();
        ls[t] += add;
        __syncthreads();
    }
    if (t < n) start[t] = (int)(ls[t] - v);
    if (t == 1023) start[n] = (int)ls[1023];
}

// pass A scatter: SoA kv = {src | dl<<17, ea 2xbf16} (8B), bk = dst bucket (1B).
// ALSO computes per-(chunk, dst-bucket) histogram cntB (folds old hist_dst kernel).
__global__ __launch_bounds__(512)
void scatter_src(const int* __restrict__ ei, const float* __restrict__ eattr,
                 const unsigned* __restrict__ cntA, const int* __restrict__ segStart,
                 uv2* __restrict__ kv, unsigned char* __restrict__ bk,
                 unsigned* __restrict__ cntB) {
    __shared__ unsigned cur[NSB];
    __shared__ unsigned hist[NSB];
    __shared__ unsigned histB[NBDST];
    __shared__ unsigned scn[256];
    __shared__ uv2 stage[SUB];
    __shared__ unsigned char stageB[SUB];
    int blk = blockIdx.x;
    int tid = threadIdx.x;
    for (int b = tid; b < NSB; b += 512)
        cur[b] = (unsigned)segStart[b] + cntA[(size_t)blk * NSB + b];
    for (int b = tid; b < NBDST; b += 512) histB[b] = 0u;
    int e0 = blk * CHUNK;
    for (int s = 0; s < NSUBB; ++s) {
        for (int b = tid; b < NSB; b += 512) hist[b] = 0u;
        __syncthreads();
        int sb0 = e0 + s * SUB;
        unsigned rk[8]; uv2 rc[8]; int bn[8]; unsigned char bb[8]; bool val[8];
        #pragma unroll
        for (int j = 0; j < 8; ++j) {
            int e = sb0 + j * 512 + tid;
            val[j] = e < EE;
            int ss = 0, dd = 0;
            fv2 ea; ea.x = 0.f; ea.y = 0.f;
            if (val[j]) {
                ss = __builtin_nontemporal_load(ei + e) % NN;
                dd = __builtin_nontemporal_load(ei + EE + e) % NN;
                ea = __builtin_nontemporal_load(reinterpret_cast<const fv2*>(eattr) + e);
            }
            bn[j] = ss >> SBSH;
            rc[j].x = (unsigned)ss | ((unsigned)(dd & (DBN - 1)) << 17);
            rc[j].y = f2bf(ea.x) | (f2bf(ea.y) << 16);
            bb[j] = (unsigned char)(dd >> DBSH);
            if (val[j]) {
                rk[j] = atomicAdd(&hist[bn[j]], 1u);
                atomicAdd(&histB[bb[j]], 1u);
            }
        }
        __syncthreads();
        if (tid < 256) scn[tid] = (tid < NSB) ? hist[tid] : 0u;
        __syncthreads();
        for (int o = 1; o < 256; o <<= 1) {
            unsigned add = 0u;
            if (tid < 256 && tid >= o) add = scn[tid - o];
            __syncthreads();
            if (tid < 256) scn[tid] += add;
            __syncthreads();
        }
        #pragma unroll
        for (int j = 0; j < 8; ++j) {
            if (val[j]) {
                unsigned ex = bn[j] ? scn[bn[j] - 1] : 0u;
                stage[ex + rk[j]]  = rc[j];
                stageB[ex + rk[j]] = bb[j];
            }
        }
        __syncthreads();
        int subCnt = (int)scn[NSB - 1];
        for (int i = tid; i < subCnt; i += 512) {
            uv2 r = stage[i];
            unsigned b = (r.x & 0x1FFFFu) >> SBSH;
            unsigned ex = b ? scn[b - 1] : 0u;
            unsigned pos = cur[b] + (unsigned)i - ex;
            kv[pos] = r;
            bk[pos] = stageB[i];
        }
        __syncthreads();
        for (int b = tid; b < NSB; b += 512) cur[b] += hist[b];
        __syncthreads();
    }
    for (int b = tid; b < NBDST; b += 512)
        cntB[(size_t)blk * NBDST + b] = histB[b];
}

// ---------- per-layer attach + bucket scatter (R17, proven 71us) ----------
__global__ __launch_bounds__(512)
void scatter_dst_att(const uv2* __restrict__ kv, const unsigned char* __restrict__ bk,
                     const unsigned* __restrict__ cntB, const int* __restrict__ bstart,
                     const int* __restrict__ segStart, const uv4* __restrict__ xlb,
                     uv4* __restrict__ recsA, unsigned short* __restrict__ recsD) {
    __shared__ unsigned cur[NBDST];
    __shared__ unsigned hist[NBDST];
    __shared__ unsigned scn[256];
    __shared__ uv4 win[2][DBN];            // 16 KB
    __shared__ uv4 stA[SUBA];              // 32 KB
    __shared__ unsigned short stD[SUBA];   // 4 KB
    __shared__ unsigned char sbin[SUBA];   // 2 KB
    __shared__ int w0s;
    int blk = blockIdx.x;
    int tid = threadIdx.x;
    int e0 = blk * CHUNK;
    if (tid == 0) w0s = 0;
    __syncthreads();
    if (tid < NSB && segStart[tid] <= e0 && e0 < segStart[tid + 1]) w0s = tid;
    __syncthreads();
    int w0 = w0s;
    int w1 = min(w0 + 1, NSB - 1);
    for (int i = tid; i < DBN; i += 512) {
        int g0 = (w0 << SBSH) + i;
        int g1 = (w1 << SBSH) + i;
        uv4 z; z.x = 0u; z.y = 0u; z.z = 0u; z.w = 0u;
        win[0][i] = (g0 < NN) ? xlb[g0] : z;
        win[1][i] = (g1 < NN) ? xlb[g1] : z;
    }
    for (int b = tid; b < NBDST; b += 512)
        cur[b] = (unsigned)bstart[b] + cntB[(size_t)blk * NBDST + b];
    __syncthreads();

    for (int s = 0; s < NSUBA; ++s) {
        for (int b = tid; b < NBDST; b += 512) hist[b] = 0u;
        __syncthreads();
        int sb0 = e0 + s * SUBA;
        unsigned rk[4]; uv4 rc[4]; unsigned short dl2[4]; int bn[4]; bool val[4];
        #pragma unroll
        for (int j = 0; j < 4; ++j) {
            int e = sb0 + j * 512 + tid;
            val[j] = e < EE;
            uv2 r; r.x = 0u; r.y = 0u;
            int b = 0;
            if (val[j]) {
                r = __builtin_nontemporal_load(kv + e);
                b = (int)bk[e];
            }
            int src = (int)(r.x & 0x1FFFFu);
            int sel = min(max((src >> SBSH) - w0, 0), 1);
            uv4 q = win[sel][src & (DBN - 1)];
            rc[j].x = r.y;
            rc[j].y = q.x;
            rc[j].z = q.y;
            rc[j].w = q.z;
            dl2[j] = (unsigned short)((r.x >> 17) & (DBN - 1));
            bn[j] = b;
            if (val[j]) rk[j] = atomicAdd(&hist[bn[j]], 1u);
        }
        __syncthreads();
        if (tid < 256) scn[tid] = (tid < NBDST) ? hist[tid] : 0u;
        __syncthreads();
        for (int o = 1; o < 256; o <<= 1) {
            unsigned add = 0u;
            if (tid < 256 && tid >= o) add = scn[tid - o];
            __syncthreads();
            if (tid < 256) scn[tid] += add;
            __syncthreads();
        }
        #pragma unroll
        for (int j = 0; j < 4; ++j) {
            if (val[j]) {
                unsigned ex = bn[j] ? scn[bn[j] - 1] : 0u;
                unsigned p = ex + rk[j];
                stA[p] = rc[j];
                stD[p] = dl2[j];
                sbin[p] = (unsigned char)bn[j];
            }
        }
        __syncthreads();
        int subCnt = (int)scn[NBDST - 1];
        for (int i = tid; i < subCnt; i += 512) {
            unsigned b = sbin[i];
            unsigned ex = b ? scn[b - 1] : 0u;
            unsigned pos = cur[b] + (unsigned)i - ex;
            recsA[pos] = stA[i];
            recsD[pos] = stD[i];
        }
        __syncthreads();
        for (int b = tid; b < NBDST; b += 512) cur[b] += hist[b];
        __syncthreads();
    }
}

// ---------- fused LDS sort + register reduce (R16, proven) ----------
__global__ __launch_bounds__(512)
void sort_reduce(const uv4* __restrict__ recsA, const unsigned short* __restrict__ recsD,
                 const int* __restrict__ bstart, const uv4* __restrict__ xrb,
                 const float* __restrict__ Wef, const float* __restrict__ attf,
                 float* __restrict__ partG) {
    __shared__ uv4 stage[SPASS];      // 32 KB
    __shared__ unsigned hist[DBN];    // 2 KB
    __shared__ unsigned scn[DBN];     // 2 KB
    int b = blockIdx.x / PSEG, s = blockIdx.x % PSEG;
    int b0 = bstart[b], b1 = bstart[b + 1], len = b1 - b0;
    int k0 = b0 + (int)(((long long)len * s) / PSEG);
    int k1 = b0 + (int)(((long long)len * (s + 1)) / PSEG);
    int tid = threadIdx.x;

    float we0[FF], we1[FF], at[FF];
    #pragma unroll
    for (int f = 0; f < FF; ++f) { we0[f] = Wef[f]; we1[f] = Wef[FF + f]; at[f] = attf[f]; }
    int n = (b << DBSH) + tid;
    float bv[FF] = {0.f, 0.f, 0.f, 0.f, 0.f, 0.f};
    if (n < NN) {
        uv4 r = xrb[n];
        bv[0] = __uint_as_float(r.x << 16);  bv[1] = __uint_as_float(r.x & 0xFFFF0000u);
        bv[2] = __uint_as_float(r.y << 16);  bv[3] = __uint_as_float(r.y & 0xFFFF0000u);
        bv[4] = __uint_as_float(r.z << 16);  bv[5] = __uint_as_float(r.z & 0xFFFF0000u);
    }
    float acc[7] = {0.f, 0.f, 0.f, 0.f, 0.f, 0.f, 0.f};

    for (int base = k0; base < k1; base += SPASS) {
        hist[tid] = 0u;
        __syncthreads();
        unsigned rk[4]; uv4 rc[4]; int dl[4]; bool val[4];
        #pragma unroll
        for (int j = 0; j < 4; ++j) {
            int k = base + j * 512 + tid;
            val[j] = k < k1;
            uv4 r; r.x = 0u; r.y = 0u; r.z = 0u; r.w = 0u;
            int d = 0;
            if (val[j]) {
                r = __builtin_nontemporal_load(recsA + k);
                d = (int)recsD[k];
            }
            rc[j] = r;
            dl[j] = d;
            if (val[j]) rk[j] = atomicAdd(&hist[d], 1u);
        }
        __syncthreads();
        scn[tid] = hist[tid];
        __syncthreads();
        for (int o = 1; o < DBN; o <<= 1) {
            unsigned add = (tid >= o) ? scn[tid - o] : 0u;
            __syncthreads();
            scn[tid] += add;
            __syncthreads();
        }
        #pragma unroll
        for (int j = 0; j < 4; ++j) {
            if (val[j]) {
                unsigned ex = dl[j] ? scn[dl[j] - 1] : 0u;
                stage[ex + rk[j]] = rc[j];
            }
        }
        __syncthreads();
        unsigned e0s = scn[tid] - hist[tid], e1s = scn[tid];
        for (unsigned j = e0s; j < e1s; ++j) {
            uv4 a = stage[j];
            float eax = __uint_as_float(a.x << 16);
            float eay = __uint_as_float(a.x & 0xFFFF0000u);
            float av[FF];
            av[0] = __uint_as_float(a.y << 16);  av[1] = __uint_as_float(a.y & 0xFFFF0000u);
            av[2] = __uint_as_float(a.z << 16);  av[3] = __uint_as_float(a.z & 0xFFFF0000u);
            av[4] = __uint_as_float(a.w << 16);  av[5] = __uint_as_float(a.w & 0xFFFF0000u);
            float logit = 0.f;
            #pragma unroll
            for (int f = 0; f < FF; ++f) {
                float m = av[f] + bv[f] + fmaf(eay, we1[f], eax * we0[f]);
                m = m >= 0.f ? m : 0.2f * m;
                logit = fmaf(at[f], m, logit);
            }
            float w = __expf(logit);
            acc[6] += w;
            #pragma unroll
            for (int f = 0; f < FF; ++f) acc[f] = fmaf(w, av[f], acc[f]);
        }
        __syncthreads();
    }
    float* dst = partG + (size_t)blockIdx.x * ACCW;
    #pragma unroll
    for (int f = 0; f < 7; ++f) dst[f * DBN + tid] = acc[f];
}

// ---------- merge partials + finalize (one block of 512 per bucket) ----------
template <int LAYER, int QSL>
__global__ __launch_bounds__(512)
void merge_finalize(const float* __restrict__ partG, const float* __restrict__ biasg,
                    const float* __restrict__ x0, const float* __restrict__ x1n0,
                    const float* __restrict__ x2,
                    float* __restrict__ h, double* __restrict__ part) {
    __shared__ double shd[16];
    int b = blockIdx.x;
    int nb0 = b << DBSH;
    int nl = threadIdx.x;
    int cnt = min(DBN, NN - nb0);
    double s1 = 0.0, s2 = 0.0;
    if (nl < cnt) {
        size_t n = nb0 + nl;
        const float* pa = partG + (size_t)b * QSL * ACCW;
        float a[7];
        #pragma unroll
        for (int f = 0; f < 7; ++f) {
            float v = 0.f;
            #pragma unroll
            for (int q = 0; q < QSL; ++q) v += pa[q * ACCW + f * DBN + nl];
            a[f] = v;
        }
        float inv = a[6] != 0.f ? 1.f / a[6] : 0.f;
        #pragma unroll
        for (int f = 0; f < FF; ++f) {
            float t = leakyf(a[f] * inv + biasg[f], 0.01f);
            t += x0[n * FF + f];
            if (LAYER == 1) t += x1n0[n * FF + f] + x2[n * FF + f];
            h[n * FF + f] = t;
            s1 += t;
            s2 += (double)t * (double)t;
        }
    }
    int wid = threadIdx.x >> 6, lane = threadIdx.x & 63;
    #pragma unroll
    for (int o = 32; o > 0; o >>= 1) {
        s1 += __shfl_down(s1, o, 64);
        s2 += __shfl_down(s2, o, 64);
    }
    if (lane == 0) { shd[wid * 2] = s1; shd[wid * 2 + 1] = s2; }
    __syncthreads();
    if (threadIdx.x == 0) {
        double t1 = 0.0, t2 = 0.0;
        #pragma unroll
        for (int w = 0; w < 8; ++w) { t1 += shd[w * 2]; t2 += shd[w * 2 + 1]; }
        part[b * 2 + 0] = t1;
        part[b * 2 + 1] = t2;
    }
}

// ---------- node transform: xlb + xrb, both bf16 packed (16B/node) ----------
template <int LAYER>
__global__ __launch_bounds__(NODE_BLOCK)
void node_transform(const float* __restrict__ xin, const double* __restrict__ Snorm,
                    const float* __restrict__ Wl, const float* __restrict__ bl,
                    const float* __restrict__ Wr, const float* __restrict__ br,
                    uv4* __restrict__ xlb, uv4* __restrict__ xrb,
                    float* __restrict__ x2out) {
    int n = blockIdx.x * blockDim.x + threadIdx.x;
    if (n >= NN) return;
    float v[FF];
    if (LAYER == 0) {
        #pragma unroll
        for (int f = 0; f < FF; ++f) v[f] = xin[n * FF + f];
    } else {
        float mu, istd;
        norm_params(Snorm, mu, istd);
        #pragma unroll
        for (int f = 0; f < FF; ++f) {
            v[f] = (xin[n * FF + f] - mu) * istd;
            x2out[n * FF + f] = v[f];
        }
    }
    float ol[FF], orr[FF];
    #pragma unroll
    for (int j = 0; j < FF; ++j) { ol[j] = bl[j]; orr[j] = br[j]; }
    #pragma unroll
    for (int k = 0; k < FF; ++k) {
        float vk = v[k];
        #pragma unroll
        for (int j = 0; j < FF; ++j) {
            ol[j]  = fmaf(vk, Wl[k * FF + j], ol[j]);
            orr[j] = fmaf(vk, Wr[k * FF + j], orr[j]);
        }
    }
    uv4 q;
    q.x = f2bf(ol[0]) | (f2bf(ol[1]) << 16);
    q.y = f2bf(ol[2]) | (f2bf(ol[3]) << 16);
    q.z = f2bf(ol[4]) | (f2bf(ol[5]) << 16);
    q.w = 0u;
    xlb[n] = q;
    uv4 r;
    r.x = f2bf(orr[0]) | (f2bf(orr[1]) << 16);
    r.y = f2bf(orr[2]) | (f2bf(orr[3]) << 16);
    r.z = f2bf(orr[4]) | (f2bf(orr[5]) << 16);
    r.w = 0u;
    xrb[n] = r;
}

// ---------- FALLBACK kernels (R12, proven) ----------
__global__ __launch_bounds__(512)
void scatter_dst(const uv2* __restrict__ kv, const unsigned char* __restrict__ bk,
                 const unsigned* __restrict__ cntB, const int* __restrict__ bstart,
                 uv2* __restrict__ recs) {
    __shared__ unsigned cur[NBDST];
    __shared__ unsigned hist[NBDST];
    __shared__ unsigned scn[256];
    __shared__ uv2 stage[SUB];
    __shared__ unsigned char sbin[SUB];
    int blk = blockIdx.x;
    int tid = threadIdx.x;
    for (int b = tid; b < NBDST; b += 512)
        cur[b] = (unsigned)bstart[b] + cntB[(size_t)blk * NBDST + b];
    int e0 = blk * CHUNK;
    for (int s = 0; s < NSUBB; ++s) {
        for (int b = tid; b < NBDST; b += 512) hist[b] = 0u;
        __syncthreads();
        int sb0 = e0 + s * SUB;
        unsigned rk[8]; uv2 rc[8]; int bn[8]; bool val[8];
        #pragma unroll
        for (int j = 0; j < 8; ++j) {
            int e = sb0 + j * 512 + tid;
            val[j] = e < EE;
            uv2 r; r.x = 0u; r.y = 0u;
            int b = 0;
            if (val[j]) {
                r = __builtin_nontemporal_load(kv + e);
                b = (int)bk[e];
            }
            rc[j] = r;
            bn[j] = b;
            if (val[j]) rk[j] = atomicAdd(&hist[bn[j]], 1u);
        }
        __syncthreads();
        if (tid < 256) scn[tid] = (tid < NBDST) ? hist[tid] : 0u;
        __syncthreads();
        for (int o = 1; o < 256; o <<= 1) {
            unsigned add = 0u;
            if (tid < 256 && tid >= o) add = scn[tid - o];
            __syncthreads();
            if (tid < 256) scn[tid] += add;
            __syncthreads();
        }
        #pragma unroll
        for (int j = 0; j < 8; ++j) {
            if (val[j]) {
                unsigned ex = bn[j] ? scn[bn[j] - 1] : 0u;
                stage[ex + rk[j]] = rc[j];
                sbin[ex + rk[j]] = (unsigned char)bn[j];
            }
        }
        __syncthreads();
        int subCnt = (int)scn[NBDST - 1];
        for (int i = tid; i < subCnt; i += 512) {
            uv2 r = stage[i];
            unsigned b = sbin[i];
            unsigned ex = b ? scn[b - 1] : 0u;
            recs[cur[b] + (unsigned)i - ex] = r;
        }
        __syncthreads();
        for (int b = tid; b < NBDST; b += 512) cur[b] += hist[b];
        __syncthreads();
    }
}

__device__ __forceinline__ void edge_math(unsigned eaw, unsigned a01, unsigned a23, unsigned a45,
                                          int dl, bool valid,
                                          float (&acc)[7][DBN], const uv4* __restrict__ xrl,
                                          const float we0[FF], const float we1[FF],
                                          const float at[FF]) {
    uv4 r = xrl[dl];
    float eax = __uint_as_float(eaw << 16);
    float eay = __uint_as_float(eaw & 0xFFFF0000u);
    float av[FF], bv[FF];
    av[0] = __uint_as_float(a01 << 16);  av[1] = __uint_as_float(a01 & 0xFFFF0000u);
    av[2] = __uint_as_float(a23 << 16);  av[3] = __uint_as_float(a23 & 0xFFFF0000u);
    av[4] = __uint_as_float(a45 << 16);  av[5] = __uint_as_float(a45 & 0xFFFF0000u);
    bv[0] = __uint_as_float(r.x << 16);  bv[1] = __uint_as_float(r.x & 0xFFFF0000u);
    bv[2] = __uint_as_float(r.y << 16);  bv[3] = __uint_as_float(r.y & 0xFFFF0000u);
    bv[4] = __uint_as_float(r.z << 16);  bv[5] = __uint_as_float(r.z & 0xFFFF0000u);
    float logit = 0.f;
    #pragma unroll
    for (int f = 0; f < FF; ++f) {
        float m = av[f] + bv[f] + fmaf(eay, we1[f], eax * we0[f]);
        m = m >= 0.f ? m : 0.2f * m;
        logit = fmaf(at[f], m, logit);
    }
    float w = __expf(logit);
    w = valid ? w : 0.f;
    atomicAdd(&acc[6][dl], w);
    #pragma unroll
    for (int f = 0; f < FF; ++f) atomicAdd(&acc[f][dl], w * av[f]);
}

template <int QSL>
__global__ __launch_bounds__(256)
void gat_gather_div(const int* __restrict__ bucketStart, const uv2* __restrict__ recs,
                    const uv4* __restrict__ xlb, const uv4* __restrict__ xrb,
                    const float* __restrict__ Wef, const float* __restrict__ attf,
                    float* __restrict__ partG) {
    __shared__ float acc[7][DBN];
    __shared__ uv4 xrl[DBN];
    int b  = blockIdx.x / QSL;
    int qq = blockIdx.x % QSL;
    int nb0 = b << DBSH;
    int cnt = min(DBN, NN - nb0);

    for (int i = threadIdx.x; i < 7 * DBN; i += 256) acc[0][i] = 0.f;
    for (int i = threadIdx.x; i < cnt; i += 256) xrl[i] = xrb[nb0 + i];
    float we0[FF], we1[FF], at[FF];
    #pragma unroll
    for (int f = 0; f < FF; ++f) { we0[f] = Wef[f]; we1[f] = Wef[FF + f]; at[f] = attf[f]; }
    __syncthreads();

    int bk0 = bucketStart[b], bk1 = bucketStart[b + 1];
    int len = bk1 - bk0;
    int k0 = bk0 + (int)(((long long)len * qq) / QSL);
    int k1 = bk0 + (int)(((long long)len * (qq + 1)) / QSL);
    int last = k1 - 1;
    for (int base = k0 + threadIdx.x * 4; base < k1; base += 1024) {
        uv2 rA = __builtin_nontemporal_load(recs + base);
        uv2 rB = __builtin_nontemporal_load(recs + min(base + 1, last));
        uv2 rC = __builtin_nontemporal_load(recs + min(base + 2, last));
        uv2 rD = __builtin_nontemporal_load(recs + min(base + 3, last));
        uv4 qA = xlb[rA.x & 0x1FFFF];
        uv4 qB = xlb[rB.x & 0x1FFFF];
        uv4 qC = xlb[rC.x & 0x1FFFF];
        uv4 qD = xlb[rD.x & 0x1FFFF];
        bool vB = base + 1 < k1, vC = base + 2 < k1, vD = base + 3 < k1;
        edge_math(rA.y, qA.x, qA.y, qA.z, (rA.x >> 17) & (DBN - 1), true, acc, xrl, we0, we1, at);
        edge_math(rB.y, qB.x, qB.y, qB.z, (rB.x >> 17) & (DBN - 1), vB,   acc, xrl, we0, we1, at);
        edge_math(rC.y, qC.x, qC.y, qC.z, (rC.x >> 17) & (DBN - 1), vC,   acc, xrl, we0, we1, at);
        edge_math(rD.y, qD.x, qD.y, qD.z, (rD.x >> 17) & (DBN - 1), vD,   acc, xrl, we0, we1, at);
    }
    __syncthreads();

    float* dst = partG + (size_t)blockIdx.x * ACCW;
    for (int i = threadIdx.x; i < ACCW; i += 256) dst[i] = acc[0][i];
}

// ---------- FFN ----------
template <int LAYER>
__global__ __launch_bounds__(NODE_BLOCK)
void node_ffn(const float* __restrict__ h, const double* __restrict__ Snorm,
              const float* __restrict__ f1W, const float* __restrict__ f1b,
              const float* __restrict__ f2W, const float* __restrict__ f2b,
              const float* __restrict__ x0, const float* __restrict__ x1n0_in,
              const float* __restrict__ x2,
              float* __restrict__ x1n0_out, float* __restrict__ gout,
              double* __restrict__ part,
              const float* __restrict__ head, float* __restrict__ dout) {
    __shared__ double sh[8];
    int n = blockIdx.x * blockDim.x + threadIdx.x;
    double s1 = 0.0, s2 = 0.0;
    if (n < NN) {
        float mu, istd;
        norm_params(Snorm, mu, istd);
        float xn[FF];
        #pragma unroll
        for (int f = 0; f < FF; ++f) xn[f] = (h[n * FF + f] - mu) * istd;

        float u[FF], w[FF];
        #pragma unroll
        for (int j = 0; j < FF; ++j) u[j] = f1b[j];
        #pragma unroll
        for (int k = 0; k < FF; ++k) {
            float vk = xn[k];
            #pragma unroll
            for (int j = 0; j < FF; ++j) u[j] = fmaf(vk, f1W[k * FF + j], u[j]);
        }
        #pragma unroll
        for (int j = 0; j < FF; ++j) u[j] = leakyf(u[j], 0.01f);
        #pragma unroll
        for (int j = 0; j < FF; ++j) w[j] = f2b[j];
        #pragma unroll
        for (int k = 0; k < FF; ++k) {
            float vk = u[k];
            #pragma unroll
            for (int j = 0; j < FF; ++j) w[j] = fmaf(vk, f2W[k * FF + j], w[j]);
        }
        #pragma unroll
        for (int f = 0; f < FF; ++f) {
            w[f] += xn[f] + x0[n * FF + f];
            if (LAYER == 1) w[f] += x2[n * FF + f] + x1n0_in[n * FF + f];
        }
        if (LAYER == 0) {
            #pragma unroll
            for (int f = 0; f < FF; ++f) {
                x1n0_out[n * FF + f] = xn[f];
                gout[n * FF + f]     = w[f];
                s1 += w[f];
                s2 += (double)w[f] * (double)w[f];
            }
        } else {
            float o1 = head[6], o2 = head[14];
            #pragma unroll
            for (int f = 0; f < FF; ++f) {
                o1 = fmaf(w[f], head[f], o1);
                o2 = fmaf(w[f], head[8 + f], o2);
            }
            dout[n * 2 + 0] = o1;
            dout[n * 2 + 1] = o2;
        }
    }
    if (LAYER == 0) {
        int wid = threadIdx.x >> 6, lane = threadIdx.x & 63;
        #pragma unroll
        for (int o = 32; o > 0; o >>= 1) {
            s1 += __shfl_down(s1, o, 64);
            s2 += __shfl_down(s2, o, 64);
        }
        if (lane == 0) { sh[wid * 2] = s1; sh[wid * 2 + 1] = s2; }
        __syncthreads();
        if (threadIdx.x == 0) {
            part[blockIdx.x * 2 + 0] = sh[0] + sh[2] + sh[4] + sh[6];
            part[blockIdx.x * 2 + 1] = sh[1] + sh[3] + sh[5] + sh[7];
        }
    }
}

// ---------------------------------------------------------------

extern "C" void kernel_launch(void* const* d_in, const int* in_sizes, int n_in,
                              void* d_out, int out_size, void* d_ws, size_t ws_size,
                              hipStream_t stream) {
    const float* x     = (const float*)d_in[0];
    const float* eattr = (const float*)d_in[1];
    const float* Wl    = (const float*)d_in[2];
    const float* bl    = (const float*)d_in[3];
    const float* Wr    = (const float*)d_in[4];
    const float* br    = (const float*)d_in[5];
    const float* We    = (const float*)d_in[6];
    const float* att   = (const float*)d_in[7];
    const float* biasg = (const float*)d_in[8];
    const float* ff1W  = (const float*)d_in[9];
    const float* ff1b  = (const float*)d_in[10];
    const float* ff2W  = (const float*)d_in[11];
    const float* ff2b  = (const float*)d_in[12];
    const float* Wresh = (const float*)d_in[13];
    const float* bresh = (const float*)d_in[14];
    const float* W1    = (const float*)d_in[15];
    const float* b1    = (const float*)d_in[16];
    const float* W2    = (const float*)d_in[17];
    const float* b2    = (const float*)d_in[18];
    const int*   ei    = (const int*)d_in[19];
    float* out = (float*)d_out;

    char* p = (char*)d_ws;
    auto alloc = [&](size_t bytes) -> char* {
        char* r = p;
        p += (bytes + 255) & ~size_t(255);
        return r;
    };

    // ---- common prefix ----
    double*   S        = (double*)alloc(8 * sizeof(double));
    float*    head     = (float*)alloc(16 * sizeof(float));
    double*   partMA   = (double*)alloc((size_t)NBDST * 2 * sizeof(double));
    double*   partMB   = (double*)alloc((size_t)NBDST * 2 * sizeof(double));
    double*   partF    = (double*)alloc((size_t)NODE_GRID * 2 * sizeof(double));
    uv4*      xlb      = (uv4*)alloc((size_t)NN * sizeof(uv4));
    uv4*      xrb      = (uv4*)alloc((size_t)NN * sizeof(uv4));
    float*    h        = (float*)alloc((size_t)NN * FF * sizeof(float));
    float*    x1n0     = (float*)alloc((size_t)NN * FF * sizeof(float));
    float*    x2       = (float*)alloc((size_t)NN * FF * sizeof(float));
    float*    g        = (float*)alloc((size_t)NN * FF * sizeof(float));
    unsigned* cntA     = (unsigned*)alloc((size_t)NBLK * NSB * sizeof(unsigned));
    unsigned* totA     = (unsigned*)alloc((size_t)NSB * sizeof(unsigned));
    int*      segStart = (int*)alloc((size_t)(NSB + 1) * sizeof(int));
    unsigned* cntB     = (unsigned*)alloc((size_t)NBLK * NBDST * sizeof(unsigned));
    unsigned* totB     = (unsigned*)alloc((size_t)NBDST * sizeof(unsigned));
    int*      bstart   = (int*)alloc((size_t)(NBDST + 1) * sizeof(int));
    uv2*      kv       = (uv2*)alloc((size_t)EE * sizeof(uv2));              // 51.2 MB
    unsigned char* bk  = (unsigned char*)alloc((size_t)EE);                  // 6.4 MB
    char* tail = p;
    // ---- fast-path tail ----
    unsigned short* recsDs = (unsigned short*)alloc((size_t)EE * 2);         // 12.8 MB
    uv4*      recsAs   = (uv4*)alloc((size_t)EE * sizeof(uv4));              // 102.4 MB
    float*    partG    = (float*)alloc((size_t)NBDST * PSEG * ACCW * sizeof(float)); // 11.2 MB
    size_t need_fast = (size_t)(p - (char*)d_ws);
    bool fast = need_fast <= ws_size;
    // ---- fallback tail (overlaps fast tail; kv overlaid for partG) ----
    uv2*   recsFb  = (uv2*)tail;
    float* partGfb = (float*)kv;

    head_prep<<<1, 64, 0, stream>>>(Wresh, bresh, W1, b1, W2, b2, head, S);

    // ---- graph-only build (cntB folded into scatter_src) ----
    hist_src<<<NBLK, 256, 0, stream>>>(ei, cntA);
    scan_bins<NSB><<<NSB, 1024, 0, stream>>>(cntA, totA);
    scan_totals<<<1, 1024, 0, stream>>>(totA, segStart, NSB);
    scatter_src<<<NBLK, 512, 0, stream>>>(ei, eattr, cntA, segStart, kv, bk, cntB);
    scan_bins<NBDST><<<NBDST, 1024, 0, stream>>>(cntB, totB);
    scan_totals<<<1, 1024, 0, stream>>>(totB, bstart, NBDST);

    if (fast) {
        // ---- layer 0 ----
        node_transform<0><<<NODE_GRID, NODE_BLOCK, 0, stream>>>(
            x, nullptr, Wl, bl, Wr, br, xlb, xrb, nullptr);
        scatter_dst_att<<<NBLK, 512, 0, stream>>>(
            kv, bk, cntB, bstart, segStart, xlb, recsAs, recsDs);
        sort_reduce<<<NBDST * PSEG, 512, 0, stream>>>(
            recsAs, recsDs, bstart, xrb, We, att, partG);
        merge_finalize<0, PSEG><<<NBDST, 512, 0, stream>>>(
            partG, biasg, x, nullptr, nullptr, h, partMA);
        finish_norm<<<1, 256, 0, stream>>>(partMA, NBDST, S + 0);
        node_ffn<0><<<NODE_GRID, NODE_BLOCK, 0, stream>>>(
            h, S + 0, ff1W, ff1b, ff2W, ff2b, x, nullptr, nullptr,
            x1n0, g, partF, nullptr, nullptr);
        finish_norm<<<1, 256, 0, stream>>>(partF, NODE_GRID, S + 2);

        // ---- layer 1 ----
        node_transform<1><<<NODE_GRID, NODE_BLOCK, 0, stream>>>(
            g, S + 2, Wl + 36, bl + 6, Wr + 36, br + 6, xlb, xrb, x2);
        scatter_dst_att<<<NBLK, 512, 0, stream>>>(
            kv, bk, cntB, bstart, segStart, xlb, recsAs, recsDs);
        sort_reduce<<<NBDST * PSEG, 512, 0, stream>>>(
            recsAs, recsDs, bstart, xrb, We + 12, att + 6, partG);
        merge_finalize<1, PSEG><<<NBDST, 512, 0, stream>>>(
            partG, biasg + 6, x, x1n0, x2, h, partMB);
        finish_norm<<<1, 256, 0, stream>>>(partMB, NBDST, S + 4);
        node_ffn<1><<<NODE_GRID, NODE_BLOCK, 0, stream>>>(
            h, S + 4, ff1W + 36, ff1b + 6, ff2W + 36, ff2b + 6, x, x1n0, x2,
            nullptr, nullptr, nullptr, head, out);
    } else {
        // ---- fallback: R12 structure ----
        scatter_dst<<<NBLK, 512, 0, stream>>>(kv, bk, cntB, bstart, recsFb);

        node_transform<0><<<NODE_GRID, NODE_BLOCK, 0, stream>>>(
            x, nullptr, Wl, bl, Wr, br, xlb, xrb, nullptr);
        gat_gather_div<QSD><<<NBDST * QSD, 256, 0, stream>>>(
            bstart, recsFb, xlb, xrb, We, att, partGfb);
        merge_finalize<0, QSD><<<NBDST, 512, 0, stream>>>(
            partGfb, biasg, x, nullptr, nullptr, h, partMA);
        finish_norm<<<1, 256, 0, stream>>>(partMA, NBDST, S + 0);
        node_ffn<0><<<NODE_GRID, NODE_BLOCK, 0, stream>>>(
            h, S + 0, ff1W, ff1b, ff2W, ff2b, x, nullptr, nullptr,
            x1n0, g, partF, nullptr, nullptr);
        finish_norm<<<1, 256, 0, stream>>>(partF, NODE_GRID, S + 2);

        node_transform<1><<<NODE_GRID, NODE_BLOCK, 0, stream>>>(
            g, S + 2, Wl + 36, bl + 6, Wr + 36, br + 6, xlb, xrb, x2);
        gat_gather_div<QSD><<<NBDST * QSD, 256, 0, stream>>>(
            bstart, recsFb, xlb, xrb, We + 12, att + 6, partGfb);
        merge_finalize<1, QSD><<<NBDST, 512, 0, stream>>>(
            partGfb, biasg + 6, x, x1n0, x2, h, partMB);
        finish_norm<<<1, 256, 0, stream>>>(partMB, NBDST, S + 4);
        node_ffn<1><<<NODE_GRID, NODE_BLOCK, 0, stream>>>(
            h, S + 4, ff1W + 36, ff1b + 6, ff2W + 36, ff2b + 6, x, x1n0, x2,
            nullptr, nullptr, nullptr, head, out);
    }
}